// Round 1
// 1420.339 us; speedup vs baseline: 1.1865x; 1.1865x over previous
//
#include <hip/hip_runtime.h>

#define B_    2
#define C_    256
#define HW_   56
#define N_    3136     // 56*56
#define NH_   8
#define D_    32
#define K1CNT 1568     // N_/2
#define K2CNT 1045     // N_//3
#define LN_EPS 1e-5f
#define SROW  3140     // padded score row; 3140%32==4
#define HBW   1024     // histogram words per row (2048 bins, u16-packed pairs)
#define CAP   960      // candidate capacity per problem (16 problems)

// ---------------- helpers ----------------
__device__ inline unsigned ordf(float f) {
    unsigned u = __float_as_uint(f);
    return u ^ (((unsigned)((int)u >> 31)) | 0x80000000u);
}

// ---------------- pooling (3 avg pools summed, zero-pad, divisor k*k) -------
__global__ void pool_kernel(const float* __restrict__ y, float* __restrict__ yp)
{
    int gid = blockIdx.x * 256 + threadIdx.x;      // b*C*N + c*N + n (n fastest)
    int n  = gid % N_;
    int bc = gid / N_;
    const float* src = y + (size_t)bc * N_;
    int x0 = n % HW_, y0 = n / HW_;
    float acc = 0.f;
#pragma unroll
    for (int dy = -3; dy <= 3; ++dy) {
        int yy = y0 + dy;
        if ((unsigned)yy >= HW_) continue;
#pragma unroll
        for (int dx = -3; dx <= 3; ++dx) {
            int xx = x0 + dx;
            if ((unsigned)xx >= HW_) continue;
            float w = 1.f / 49.f;
            if (dy >= -2 && dy <= 2 && dx >= -2 && dx <= 2) w += 1.f / 25.f;
            if (dy >= -1 && dy <= 1 && dx >= -1 && dx <= 1) w += 1.f / 9.f;
            acc += w * src[yy * HW_ + xx];
        }
    }
    yp[gid] = acc;
}

// ---------------- layernorm over C, writes transposed [B,C,N] ---------------
__global__ void ln_kernel(const float* __restrict__ yp, const float* __restrict__ lnw,
                          const float* __restrict__ lnb, float* __restrict__ yfT)
{
    __shared__ float wr[8];
    __shared__ float stats[2];
    int idx = blockIdx.x;            // b*N + n
    int b = idx / N_, n = idx % N_;
    int c = threadIdx.x;
    size_t off = ((size_t)b * C_ + c) * N_ + n;
    float v = yp[off];
    float s = v, q = v * v;
    int lane = threadIdx.x & 63, wid = threadIdx.x >> 6;
#pragma unroll
    for (int d = 32; d; d >>= 1) { s += __shfl_down(s, d, 64); q += __shfl_down(q, d, 64); }
    if (lane == 0) { wr[wid] = s; wr[4 + wid] = q; }
    __syncthreads();
    if (threadIdx.x == 0) {
        float ts = wr[0] + wr[1] + wr[2] + wr[3];
        float tq = wr[4] + wr[5] + wr[6] + wr[7];
        float mu = ts * (1.f / C_);
        float var = tq * (1.f / C_) - mu * mu;
        stats[0] = mu; stats[1] = rsqrtf(var + LN_EPS);
    }
    __syncthreads();
    yfT[off] = (v - stats[0]) * stats[1] * lnw[c] + lnb[c];
}

// ---------------- GEMM: out = A(AT layout [B,C,N]) @ W[O,K]^T + bias --------
__global__ __launch_bounds__(256) void gemm_qkv(
    const float* __restrict__ A, const float* __restrict__ W,
    const float* __restrict__ bias, float* __restrict__ dst0,
    float* __restrict__ dst1, float scale)
{
    __shared__ float As[16][64];
    __shared__ float Ws[16][68];
    int tid = threadIdx.x;
    int m0 = blockIdx.x * 64;
    int b = m0 / N_, n0 = m0 % N_;
    int o0 = blockIdx.y * 64;
    const float* Ab = A + (size_t)b * C_ * N_;
    float acc[4][4] = {};
    int la_k = tid >> 4;
    int la_m = (tid & 15) * 4;
    int lw_o = tid >> 2;
    int lw_k = (tid & 3) * 4;
    int u  = tid & 15;
    int v_ = tid >> 4;
    for (int kt = 0; kt < 16; ++kt) {
        int k0 = kt * 16;
        float4 av = *(const float4*)&Ab[(size_t)(k0 + la_k) * N_ + n0 + la_m];
        float4 wv = *(const float4*)&W[(size_t)(o0 + lw_o) * C_ + k0 + lw_k];
        __syncthreads();
        *(float4*)&As[la_k][la_m] = av;
        Ws[lw_k + 0][lw_o] = wv.x; Ws[lw_k + 1][lw_o] = wv.y;
        Ws[lw_k + 2][lw_o] = wv.z; Ws[lw_k + 3][lw_o] = wv.w;
        __syncthreads();
#pragma unroll
        for (int k = 0; k < 16; ++k) {
            float4 wf = *(const float4*)&Ws[k][u * 4];
            float a0 = As[k][v_], a1 = As[k][v_ + 16], a2 = As[k][v_ + 32], a3 = As[k][v_ + 48];
            acc[0][0] += wf.x * a0; acc[0][1] += wf.x * a1; acc[0][2] += wf.x * a2; acc[0][3] += wf.x * a3;
            acc[1][0] += wf.y * a0; acc[1][1] += wf.y * a1; acc[1][2] += wf.y * a2; acc[1][3] += wf.y * a3;
            acc[2][0] += wf.z * a0; acc[2][1] += wf.z * a1; acc[2][2] += wf.z * a2; acc[2][3] += wf.z * a3;
            acc[3][0] += wf.w * a0; acc[3][1] += wf.w * a1; acc[3][2] += wf.w * a2; acc[3][3] += wf.w * a3;
        }
    }
    int oc = o0 + u * 4;
    float b0v = bias[oc], b1v = bias[oc + 1], b2v = bias[oc + 2], b3v = bias[oc + 3];
    float* dst = dst0; int c2 = oc;
    if (dst1 && oc >= C_) { dst = dst1; c2 = oc - C_; }
    int h = c2 >> 5, d0 = c2 & 31;
    size_t base = ((size_t)b * NH_ + h) * N_ * D_;
#pragma unroll
    for (int j = 0; j < 4; ++j) {
        int n = n0 + v_ + j * 16;
        float4 val;
        val.x = (acc[0][j] + b0v) * scale;
        val.y = (acc[1][j] + b1v) * scale;
        val.z = (acc[2][j] + b2v) * scale;
        val.w = (acc[3][j] + b3v) * scale;
        *(float4*)&dst[base + (size_t)n * D_ + d0] = val;
    }
}

__global__ __launch_bounds__(256) void gemm_proj(
    const float* __restrict__ A, const float* __restrict__ W,
    const float* __restrict__ bias, float* __restrict__ out)
{
    __shared__ float As[16][64];
    __shared__ float Ws[16][68];
    int tid = threadIdx.x;
    int m0 = blockIdx.x * 64;
    int b = m0 / N_, n0 = m0 % N_;
    int o0 = blockIdx.y * 64;
    const float* Ab = A + (size_t)b * C_ * N_;
    float acc[4][4] = {};
    int la_k = tid >> 4;
    int la_m = (tid & 15) * 4;
    int lw_o = tid >> 2;
    int lw_k = (tid & 3) * 4;
    int u  = tid & 15;
    int v_ = tid >> 4;
    for (int kt = 0; kt < 16; ++kt) {
        int k0 = kt * 16;
        float4 av = *(const float4*)&Ab[(size_t)(k0 + la_k) * N_ + n0 + la_m];
        float4 wv = *(const float4*)&W[(size_t)(o0 + lw_o) * C_ + k0 + lw_k];
        __syncthreads();
        *(float4*)&As[la_k][la_m] = av;
        Ws[lw_k + 0][lw_o] = wv.x; Ws[lw_k + 1][lw_o] = wv.y;
        Ws[lw_k + 2][lw_o] = wv.z; Ws[lw_k + 3][lw_o] = wv.w;
        __syncthreads();
#pragma unroll
        for (int k = 0; k < 16; ++k) {
            float4 af = *(const float4*)&As[k][u * 4];
            float w0 = Ws[k][v_], w1 = Ws[k][v_ + 16], w2 = Ws[k][v_ + 32], w3 = Ws[k][v_ + 48];
            acc[0][0] += w0 * af.x; acc[0][1] += w0 * af.y; acc[0][2] += w0 * af.z; acc[0][3] += w0 * af.w;
            acc[1][0] += w1 * af.x; acc[1][1] += w1 * af.y; acc[1][2] += w1 * af.z; acc[1][3] += w1 * af.w;
            acc[2][0] += w2 * af.x; acc[2][1] += w2 * af.y; acc[2][2] += w2 * af.z; acc[2][3] += w2 * af.w;
            acc[3][0] += w3 * af.x; acc[3][1] += w3 * af.y; acc[3][2] += w3 * af.z; acc[3][3] += w3 * af.w;
        }
    }
#pragma unroll
    for (int i = 0; i < 4; ++i) {
        int o = o0 + v_ + i * 16;
        float bb = bias[o];
        float4 val;
        val.x = acc[i][0] + bb; val.y = acc[i][1] + bb;
        val.z = acc[i][2] + bb; val.w = acc[i][3] + bb;
        *(float4*)&out[((size_t)b * C_ + o) * N_ + n0 + u * 4] = val;
    }
}

// ---------------- fused attention (1024 threads, 16 waves) ----------------
// LDS layout:
//   [0,100480)        S: 8 rows x 3140 fp32 scores (then signed exp markers)
//   [100480,161920)   X: hist (8x1024 u32, u16-packed) | cand (16x960 u32) | red (16x256 f32)
//   [161920,163304)   M: misc
struct AttnMisc {
    float rowmax[8];
    unsigned thrBin[16];
    int selrM[16];
    unsigned thrU[16];
    unsigned cntM[16];
    float coef[16];
    float pp[2];
    float wred[256];     // 16 waves x 16 slots
};

#define REFINE_BODY(NV)                                                    \
    {                                                                      \
        unsigned vv[NV]; unsigned act = 0;                                 \
        _Pragma("unroll")                                                  \
        for (int t = 0; t < NV; ++t) {                                     \
            int idx = lane + (t << 6);                                     \
            bool ok = idx < cnt;                                           \
            vv[t] = ok ? cp[idx] : 0u;                                     \
            if (ok) act |= 1u << t;                                        \
        }                                                                  \
        for (int b = 20; b >= 0; --b) {                                    \
            unsigned msk = 0, c = 0;                                       \
            _Pragma("unroll")                                              \
            for (int t = 0; t < NV; ++t) {                                 \
                bool p = ((act >> t) & 1u) && ((vv[t] >> b) & 1u);         \
                c += (unsigned)__popcll(__ballot(p));                      \
                if (p) msk |= 1u << t;                                     \
            }                                                              \
            if (c >= kk) { act = msk; bits |= 1u << b; }                   \
            else { kk -= c; act &= ~msk; }                                 \
        }                                                                  \
    }

__global__ __launch_bounds__(1024, 4) void attn_kernel(
    const float* __restrict__ qh, const float* __restrict__ kh, const float* __restrict__ vh,
    const float* __restrict__ p1p, const float* __restrict__ p2p,
    float* __restrict__ aoT)
{
    extern __shared__ char smem[];
    float*    S    = (float*)smem;
    unsigned* hist = (unsigned*)(smem + 100480);
    unsigned* cand = (unsigned*)(smem + 100480);
    float*    red  = (float*)(smem + 100480);
    AttnMisc* M    = (AttnMisc*)(smem + 161920);

    int tid = threadIdx.x, lane = tid & 63, wid = tid >> 6;
    int bh = blockIdx.y, n0 = blockIdx.x * 8;
    size_t bhN = (size_t)bh * N_;

    if (tid < 16) M->cntM[tid] = 0u;
    if (tid == 0) { M->pp[0] = p1p[0]; M->pp[1] = p2p[0]; }
    for (int i = tid; i < 8 * HBW; i += 1024) hist[i] = 0u;
    __syncthreads();

    // ---- P0: scores + rowmax + 11-bit packed histogram ----
    // q address is block-uniform -> scalar (s_load) reads, no LDS traffic.
    const float* qrow = qh + (bhN + n0) * D_;
    float lmax[8];
#pragma unroll
    for (int r = 0; r < 8; ++r) lmax[r] = -3.4e38f;
    for (int i = 0; i < 4; ++i) {
        int j = tid + (i << 10);
        if (j < N_) {
            const float4* kp = (const float4*)(kh + (bhN + j) * D_);
            float4 k4[8];
#pragma unroll
            for (int q = 0; q < 8; ++q) k4[q] = kp[q];
#pragma unroll
            for (int r = 0; r < 8; ++r) {
                const float4* qp = (const float4*)(qrow + r * D_);
                float s = 0.f;
#pragma unroll
                for (int q = 0; q < 8; ++q) {
                    float4 q4 = qp[q];
                    s += q4.x * k4[q].x + q4.y * k4[q].y + q4.z * k4[q].z + q4.w * k4[q].w;
                }
                S[r * SROW + j] = s;
                lmax[r] = fmaxf(lmax[r], s);
                unsigned bin = ordf(s) >> 21;     // sign+exp+2 mantissa bits: spread
                atomicAdd(&hist[(r << 10) + (bin >> 1)], 1u << ((bin & 1) << 4));
            }
        }
    }
#pragma unroll
    for (int r = 0; r < 8; ++r) {
        float v = lmax[r];
#pragma unroll
        for (int d = 32; d; d >>= 1) v = fmaxf(v, __shfl_down(v, d, 64));
        if (lane == 0) M->wred[wid * 16 + r] = v;
    }
    __syncthreads();

    // ---- rowmax finalize + histogram search (wave w -> problem w) ----
    if (tid < 8) {
        float mm = -3.4e38f;
        for (int w = 0; w < 16; ++w) mm = fmaxf(mm, M->wred[w * 16 + tid]);
        M->rowmax[tid] = mm;
    }
    {
        int prob = wid;
        int r = prob >> 1;
        int k = (prob & 1) ? K2CNT : K1CNT;
        const unsigned* hrow = hist + (r << 10) + (lane << 4);
        uint4 ha = *(const uint4*)(hrow + 0);
        uint4 hb = *(const uint4*)(hrow + 4);
        uint4 hc = *(const uint4*)(hrow + 8);
        uint4 hd = *(const uint4*)(hrow + 12);
        unsigned hh[16] = { ha.x, ha.y, ha.z, ha.w, hb.x, hb.y, hb.z, hb.w,
                            hc.x, hc.y, hc.z, hc.w, hd.x, hd.y, hd.z, hd.w };
        unsigned usum = 0;
#pragma unroll
        for (int t = 0; t < 16; ++t) usum += hh[t];
        int ltot = (int)((usum & 0xFFFFu) + (usum >> 16));   // no cross-half carry: row total <= 3136
        int s = ltot;
#pragma unroll
        for (int d = 1; d < 64; d <<= 1) {
            int o = __shfl_down(s, d, 64);
            if (lane + d < 64) s += o;
        }
        int after = s - ltot;            // counts in higher lanes' (larger) bins
        if (after < k && after + ltot >= k) {   // crossing lane (unique)
            int g = after, b0 = -1, selr = 0;
#pragma unroll
            for (int m = 31; m >= 0; --m) {
                unsigned w = hh[m >> 1];
                int cm = (m & 1) ? (int)(w >> 16) : (int)(w & 0xFFFFu);
                g += cm;
                if (b0 < 0 && g >= k) { b0 = (lane << 5) + m; selr = k - (g - cm); }
            }
            M->thrBin[prob] = (unsigned)b0;
            M->selrM[prob] = selr;
        }
    }
    __syncthreads();

    // ---- P1: gather candidates sharing the selected 11-bit prefix ----
    unsigned tb[16];
#pragma unroll
    for (int p = 0; p < 16; ++p) tb[p] = M->thrBin[p];
    {
        int j4 = tid << 2;
        if (j4 < N_) {                       // 784 threads, exact (3136 = 784*4)
#pragma unroll
            for (int r = 0; r < 8; ++r) {
                float4 sv = *(const float4*)&S[r * SROW + j4];
                float sa[4] = { sv.x, sv.y, sv.z, sv.w };
#pragma unroll
                for (int t = 0; t < 4; ++t) {
                    unsigned uu = ordf(sa[t]);
                    unsigned bin = uu >> 21;
                    if (bin == tb[2 * r]) {
                        unsigned idx = atomicAdd(&M->cntM[2 * r], 1u);
                        if (idx < CAP) cand[(2 * r) * CAP + idx] = uu;
                    }
                    if (bin == tb[2 * r + 1]) {
                        unsigned idx = atomicAdd(&M->cntM[2 * r + 1], 1u);
                        if (idx < CAP) cand[(2 * r + 1) * CAP + idx] = uu;
                    }
                }
            }
        }
    }
    __syncthreads();

    // ---- refine: ballot-radix over remaining 21 bits, wave w -> problem w ----
    {
        int prob = wid;
        int cnt = (int)M->cntM[prob]; if (cnt > CAP) cnt = CAP;
        unsigned kk = (unsigned)M->selrM[prob];
        unsigned bin = M->thrBin[prob];
        const unsigned* cp = cand + prob * CAP;
        unsigned bits = 0;
        if (cnt <= 64)       REFINE_BODY(1)
        else if (cnt <= 192) REFINE_BODY(3)
        else                 REFINE_BODY(15)
        if (lane == 0) M->thrU[prob] = (bin << 21) | bits;
    }
    __syncthreads();

    // ---- masked exp sums + signed markers written in place (vectorized) ----
    unsigned t1r[8], t2r[8]; float rm[8];
#pragma unroll
    for (int r = 0; r < 8; ++r) {
        t1r[r] = M->thrU[2 * r];
        t2r[r] = M->thrU[2 * r + 1];
        rm[r] = M->rowmax[r];
    }
    float ls1a[8] = {}, ls2a[8] = {};
    {
        int j4 = tid << 2;
        if (j4 < N_) {
#pragma unroll
            for (int r = 0; r < 8; ++r) {
                float4 sv = *(const float4*)&S[r * SROW + j4];
                float sa[4] = { sv.x, sv.y, sv.z, sv.w };
#pragma unroll
                for (int t = 0; t < 4; ++t) {
                    float a = sa[t];
                    unsigned uu = ordf(a);
                    float outv = 0.f;
                    if (uu >= t1r[r]) {
                        float w = __expf(a - rm[r]);
                        ls1a[r] += w;
                        if (uu >= t2r[r]) { ls2a[r] += w; outv = w; }
                        else outv = -w;
                    }
                    sa[t] = outv;
                }
                *(float4*)&S[r * SROW + j4] = make_float4(sa[0], sa[1], sa[2], sa[3]);
            }
        }
    }
#pragma unroll
    for (int r = 0; r < 8; ++r) {
        float a1 = ls1a[r], a2 = ls2a[r];
#pragma unroll
        for (int d = 32; d; d >>= 1) { a1 += __shfl_down(a1, d, 64); a2 += __shfl_down(a2, d, 64); }
        if (lane == 0) { M->wred[wid * 16 + r * 2] = a1; M->wred[wid * 16 + r * 2 + 1] = a2; }
    }
    __syncthreads();
    if (tid < 16) {
        float ssum = 0.f;
        for (int w = 0; w < 16; ++w) ssum += M->wred[w * 16 + tid];
        M->coef[tid] = ((tid & 1) ? M->pp[1] : M->pp[0]) / ssum;
    }
    __syncthreads();

    // ---- AV: 32-j groups, V direct from global (L2-resident), reg accumulate ----
    float c1v[8], c12v[8];
#pragma unroll
    for (int r = 0; r < 8; ++r) {
        float a = M->coef[2 * r], b2 = M->coef[2 * r + 1];
        c1v[r] = a; c12v[r] = a + b2;
    }
    int jj4 = lane >> 3, dq = lane & 7;
    float4 acc[8];
#pragma unroll
    for (int r = 0; r < 8; ++r) acc[r] = make_float4(0.f, 0.f, 0.f, 0.f);
    const float* vbase = vh + bhN * D_ + (dq << 2);
    for (int g = wid; g < 98; g += 16) {        // 98 groups of 32 j (3136 = 98*32)
        int jb = (g << 5) + (jj4 << 2);
        float4 v0 = *(const float4*)(vbase + (size_t)(jb + 0) * D_);
        float4 v1 = *(const float4*)(vbase + (size_t)(jb + 1) * D_);
        float4 v2 = *(const float4*)(vbase + (size_t)(jb + 2) * D_);
        float4 v3 = *(const float4*)(vbase + (size_t)(jb + 3) * D_);
#pragma unroll
        for (int r = 0; r < 8; ++r) {
            float4 s4 = *(const float4*)&S[r * SROW + jb];
            float c0 = (s4.x > 0.f) ? s4.x * c12v[r] : -s4.x * c1v[r];
            float c1 = (s4.y > 0.f) ? s4.y * c12v[r] : -s4.y * c1v[r];
            float c2 = (s4.z > 0.f) ? s4.z * c12v[r] : -s4.z * c1v[r];
            float c3 = (s4.w > 0.f) ? s4.w * c12v[r] : -s4.w * c1v[r];
            acc[r].x += c0 * v0.x + c1 * v1.x + c2 * v2.x + c3 * v3.x;
            acc[r].y += c0 * v0.y + c1 * v1.y + c2 * v2.y + c3 * v3.y;
            acc[r].z += c0 * v0.z + c1 * v1.z + c2 * v2.z + c3 * v3.z;
            acc[r].w += c0 * v0.w + c1 * v1.w + c2 * v2.w + c3 * v3.w;
        }
    }
    // reduce over jj4 groups (xor 8,16,32)
#pragma unroll
    for (int m = 8; m < 64; m <<= 1) {
#pragma unroll
        for (int r = 0; r < 8; ++r) {
            acc[r].x += __shfl_xor(acc[r].x, m, 64);
            acc[r].y += __shfl_xor(acc[r].y, m, 64);
            acc[r].z += __shfl_xor(acc[r].z, m, 64);
            acc[r].w += __shfl_xor(acc[r].w, m, 64);
        }
    }
    if (lane < 8) {
#pragma unroll
        for (int r = 0; r < 8; ++r)
            *(float4*)&red[(wid << 8) + (r << 5) + (lane << 2)] = acc[r];
    }
    __syncthreads();
    if (tid < 256) {
        float o = 0.f;
#pragma unroll
        for (int w = 0; w < 16; ++w) o += red[(w << 8) + tid];
        int r = tid >> 5, d = tid & 31;
        int b = bh >> 3, h = bh & 7;
        aoT[((size_t)(b * C_ + h * 32 + d)) * N_ + n0 + r] = o;
    }
}

static const int ATTN_SMEM = 161920 + (int)sizeof(AttnMisc);

extern "C" void kernel_launch(void* const* d_in, const int* in_sizes, int n_in,
                              void* d_out, int out_size, void* d_ws, size_t ws_size,
                              hipStream_t stream)
{
    (void)in_sizes; (void)n_in; (void)out_size; (void)ws_size;
    const float* x    = (const float*)d_in[0];
    const float* y    = (const float*)d_in[1];
    const float* q_w  = (const float*)d_in[2];
    const float* q_b  = (const float*)d_in[3];
    const float* kv_w = (const float*)d_in[4];
    const float* kv_b = (const float*)d_in[5];
    const float* p_w  = (const float*)d_in[6];
    const float* p_b  = (const float*)d_in[7];
    const float* lnw  = (const float*)d_in[8];
    const float* lnb  = (const float*)d_in[9];
    const float* a1p  = (const float*)d_in[10];
    const float* a2p  = (const float*)d_in[11];
    float* out = (float*)d_out;

    float* ws = (float*)d_ws;
    const size_t PLANE = (size_t)B_ * C_ * N_;
    float* yp  = ws;
    float* yfT = ws + PLANE;
    float* qh_ = ws + 2 * PLANE;
    float* kh_ = ws + 3 * PLANE;
    float* vh_ = ws + 4 * PLANE;
    float* aoT = ws + 5 * PLANE;

    pool_kernel<<<dim3((unsigned)(PLANE / 256)), 256, 0, stream>>>(y, yp);
    ln_kernel<<<dim3(B_ * N_), 256, 0, stream>>>(yp, lnw, lnb, yfT);
    gemm_qkv<<<dim3(98, 4), 256, 0, stream>>>(x, q_w, q_b, qh_, nullptr, 0.17677669529663687f);
    gemm_qkv<<<dim3(98, 8), 256, 0, stream>>>(yfT, kv_w, kv_b, kh_, vh_, 1.0f);
    hipFuncSetAttribute(reinterpret_cast<const void*>(attn_kernel),
                        hipFuncAttributeMaxDynamicSharedMemorySize, ATTN_SMEM);
    attn_kernel<<<dim3(N_ / 8, B_ * NH_), 1024, ATTN_SMEM, stream>>>(qh_, kh_, vh_, a1p, a2p, aoT);
    gemm_proj<<<dim3(98, 4), 256, 0, stream>>>(aoT, p_w, p_b, out);
}

// Round 2
// 1198.691 us; speedup vs baseline: 1.4059x; 1.1849x over previous
//
#include <hip/hip_runtime.h>

#define B_    2
#define C_    256
#define HW_   56
#define N_    3136     // 56*56
#define NH_   8
#define D_    32
#define K1CNT 1568     // N_/2
#define K2CNT 1045     // N_//3
#define LN_EPS 1e-5f
#define SROW  3140     // padded score row; 3140%32==4
#define ROWS  4        // q-rows per block (halved for 2 blocks/CU occupancy)
#define PROBS 8        // ROWS * 2 top-k problems
#define HISTW 4096     // ROWS * 1024 words (2048 bins, u16-packed pairs)
#define CAP   896      // candidate capacity per problem (8 problems)

// LDS budget (per block): S 50240 | hist 16384 / cand 28672 / red 8192 (shared) | misc 1384
// total = 50240 + 28672 + 1384 = 80296 <= 81920  ->  2 blocks/CU

// ---------------- helpers ----------------
__device__ inline unsigned ordf(float f) {
    unsigned u = __float_as_uint(f);
    return u ^ (((unsigned)((int)u >> 31)) | 0x80000000u);
}

// ---------------- pooling (3 avg pools summed, zero-pad, divisor k*k) -------
__global__ void pool_kernel(const float* __restrict__ y, float* __restrict__ yp)
{
    int gid = blockIdx.x * 256 + threadIdx.x;      // b*C*N + c*N + n (n fastest)
    int n  = gid % N_;
    int bc = gid / N_;
    const float* src = y + (size_t)bc * N_;
    int x0 = n % HW_, y0 = n / HW_;
    float acc = 0.f;
#pragma unroll
    for (int dy = -3; dy <= 3; ++dy) {
        int yy = y0 + dy;
        if ((unsigned)yy >= HW_) continue;
#pragma unroll
        for (int dx = -3; dx <= 3; ++dx) {
            int xx = x0 + dx;
            if ((unsigned)xx >= HW_) continue;
            float w = 1.f / 49.f;
            if (dy >= -2 && dy <= 2 && dx >= -2 && dx <= 2) w += 1.f / 25.f;
            if (dy >= -1 && dy <= 1 && dx >= -1 && dx <= 1) w += 1.f / 9.f;
            acc += w * src[yy * HW_ + xx];
        }
    }
    yp[gid] = acc;
}

// ---------------- layernorm over C, writes transposed [B,C,N] ---------------
__global__ void ln_kernel(const float* __restrict__ yp, const float* __restrict__ lnw,
                          const float* __restrict__ lnb, float* __restrict__ yfT)
{
    __shared__ float wr[8];
    __shared__ float stats[2];
    int idx = blockIdx.x;            // b*N + n
    int b = idx / N_, n = idx % N_;
    int c = threadIdx.x;
    size_t off = ((size_t)b * C_ + c) * N_ + n;
    float v = yp[off];
    float s = v, q = v * v;
    int lane = threadIdx.x & 63, wid = threadIdx.x >> 6;
#pragma unroll
    for (int d = 32; d; d >>= 1) { s += __shfl_down(s, d, 64); q += __shfl_down(q, d, 64); }
    if (lane == 0) { wr[wid] = s; wr[4 + wid] = q; }
    __syncthreads();
    if (threadIdx.x == 0) {
        float ts = wr[0] + wr[1] + wr[2] + wr[3];
        float tq = wr[4] + wr[5] + wr[6] + wr[7];
        float mu = ts * (1.f / C_);
        float var = tq * (1.f / C_) - mu * mu;
        stats[0] = mu; stats[1] = rsqrtf(var + LN_EPS);
    }
    __syncthreads();
    yfT[off] = (v - stats[0]) * stats[1] * lnw[c] + lnb[c];
}

// ---------------- GEMM: out = A(AT layout [B,C,N]) @ W[O,K]^T + bias --------
__global__ __launch_bounds__(256) void gemm_qkv(
    const float* __restrict__ A, const float* __restrict__ W,
    const float* __restrict__ bias, float* __restrict__ dst0,
    float* __restrict__ dst1, float scale)
{
    __shared__ float As[16][64];
    __shared__ float Ws[16][68];
    int tid = threadIdx.x;
    int m0 = blockIdx.x * 64;
    int b = m0 / N_, n0 = m0 % N_;
    int o0 = blockIdx.y * 64;
    const float* Ab = A + (size_t)b * C_ * N_;
    float acc[4][4] = {};
    int la_k = tid >> 4;
    int la_m = (tid & 15) * 4;
    int lw_o = tid >> 2;
    int lw_k = (tid & 3) * 4;
    int u  = tid & 15;
    int v_ = tid >> 4;
    for (int kt = 0; kt < 16; ++kt) {
        int k0 = kt * 16;
        float4 av = *(const float4*)&Ab[(size_t)(k0 + la_k) * N_ + n0 + la_m];
        float4 wv = *(const float4*)&W[(size_t)(o0 + lw_o) * C_ + k0 + lw_k];
        __syncthreads();
        *(float4*)&As[la_k][la_m] = av;
        Ws[lw_k + 0][lw_o] = wv.x; Ws[lw_k + 1][lw_o] = wv.y;
        Ws[lw_k + 2][lw_o] = wv.z; Ws[lw_k + 3][lw_o] = wv.w;
        __syncthreads();
#pragma unroll
        for (int k = 0; k < 16; ++k) {
            float4 wf = *(const float4*)&Ws[k][u * 4];
            float a0 = As[k][v_], a1 = As[k][v_ + 16], a2 = As[k][v_ + 32], a3 = As[k][v_ + 48];
            acc[0][0] += wf.x * a0; acc[0][1] += wf.x * a1; acc[0][2] += wf.x * a2; acc[0][3] += wf.x * a3;
            acc[1][0] += wf.y * a0; acc[1][1] += wf.y * a1; acc[1][2] += wf.y * a2; acc[1][3] += wf.y * a3;
            acc[2][0] += wf.z * a0; acc[2][1] += wf.z * a1; acc[2][2] += wf.z * a2; acc[2][3] += wf.z * a3;
            acc[3][0] += wf.w * a0; acc[3][1] += wf.w * a1; acc[3][2] += wf.w * a2; acc[3][3] += wf.w * a3;
        }
    }
    int oc = o0 + u * 4;
    float b0v = bias[oc], b1v = bias[oc + 1], b2v = bias[oc + 2], b3v = bias[oc + 3];
    float* dst = dst0; int c2 = oc;
    if (dst1 && oc >= C_) { dst = dst1; c2 = oc - C_; }
    int h = c2 >> 5, d0 = c2 & 31;
    size_t base = ((size_t)b * NH_ + h) * N_ * D_;
#pragma unroll
    for (int j = 0; j < 4; ++j) {
        int n = n0 + v_ + j * 16;
        float4 val;
        val.x = (acc[0][j] + b0v) * scale;
        val.y = (acc[1][j] + b1v) * scale;
        val.z = (acc[2][j] + b2v) * scale;
        val.w = (acc[3][j] + b3v) * scale;
        *(float4*)&dst[base + (size_t)n * D_ + d0] = val;
    }
}

__global__ __launch_bounds__(256) void gemm_proj(
    const float* __restrict__ A, const float* __restrict__ W,
    const float* __restrict__ bias, float* __restrict__ out)
{
    __shared__ float As[16][64];
    __shared__ float Ws[16][68];
    int tid = threadIdx.x;
    int m0 = blockIdx.x * 64;
    int b = m0 / N_, n0 = m0 % N_;
    int o0 = blockIdx.y * 64;
    const float* Ab = A + (size_t)b * C_ * N_;
    float acc[4][4] = {};
    int la_k = tid >> 4;
    int la_m = (tid & 15) * 4;
    int lw_o = tid >> 2;
    int lw_k = (tid & 3) * 4;
    int u  = tid & 15;
    int v_ = tid >> 4;
    for (int kt = 0; kt < 16; ++kt) {
        int k0 = kt * 16;
        float4 av = *(const float4*)&Ab[(size_t)(k0 + la_k) * N_ + n0 + la_m];
        float4 wv = *(const float4*)&W[(size_t)(o0 + lw_o) * C_ + k0 + lw_k];
        __syncthreads();
        *(float4*)&As[la_k][la_m] = av;
        Ws[lw_k + 0][lw_o] = wv.x; Ws[lw_k + 1][lw_o] = wv.y;
        Ws[lw_k + 2][lw_o] = wv.z; Ws[lw_k + 3][lw_o] = wv.w;
        __syncthreads();
#pragma unroll
        for (int k = 0; k < 16; ++k) {
            float4 af = *(const float4*)&As[k][u * 4];
            float w0 = Ws[k][v_], w1 = Ws[k][v_ + 16], w2 = Ws[k][v_ + 32], w3 = Ws[k][v_ + 48];
            acc[0][0] += w0 * af.x; acc[0][1] += w0 * af.y; acc[0][2] += w0 * af.z; acc[0][3] += w0 * af.w;
            acc[1][0] += w1 * af.x; acc[1][1] += w1 * af.y; acc[1][2] += w1 * af.z; acc[1][3] += w1 * af.w;
            acc[2][0] += w2 * af.x; acc[2][1] += w2 * af.y; acc[2][2] += w2 * af.z; acc[2][3] += w2 * af.w;
            acc[3][0] += w3 * af.x; acc[3][1] += w3 * af.y; acc[3][2] += w3 * af.z; acc[3][3] += w3 * af.w;
        }
    }
#pragma unroll
    for (int i = 0; i < 4; ++i) {
        int o = o0 + v_ + i * 16;
        float bb = bias[o];
        float4 val;
        val.x = acc[i][0] + bb; val.y = acc[i][1] + bb;
        val.z = acc[i][2] + bb; val.w = acc[i][3] + bb;
        *(float4*)&out[((size_t)b * C_ + o) * N_ + n0 + u * 4] = val;
    }
}

// ---------------- fused attention (1024 threads, 16 waves, 4 q-rows) --------
struct AttnMisc {
    float rowmax[8];
    unsigned thrBin[16];
    int selrM[16];
    unsigned thrU[16];
    unsigned cntM[16];
    float coef[16];
    float pp[2];
    float wred[256];     // 16 waves x 16 slots
};

#define REFINE_BODY(NV)                                                    \
    {                                                                      \
        unsigned vv[NV]; unsigned act = 0;                                 \
        _Pragma("unroll")                                                  \
        for (int t = 0; t < NV; ++t) {                                     \
            int idx = lane + (t << 6);                                     \
            bool ok = idx < cnt;                                           \
            vv[t] = ok ? cp[idx] : 0u;                                     \
            if (ok) act |= 1u << t;                                        \
        }                                                                  \
        for (int b = 20; b >= 0; --b) {                                    \
            unsigned msk = 0, c = 0;                                       \
            _Pragma("unroll")                                              \
            for (int t = 0; t < NV; ++t) {                                 \
                bool p = ((act >> t) & 1u) && ((vv[t] >> b) & 1u);         \
                c += (unsigned)__popcll(__ballot(p));                      \
                if (p) msk |= 1u << t;                                     \
            }                                                              \
            if (c >= kk) { act = msk; bits |= 1u << b; }                   \
            else { kk -= c; act &= ~msk; }                                 \
        }                                                                  \
    }

__global__ __launch_bounds__(1024, 8) void attn_kernel(
    const float* __restrict__ qh, const float* __restrict__ kh, const float* __restrict__ vh,
    const float* __restrict__ p1p, const float* __restrict__ p2p,
    float* __restrict__ aoT)
{
    extern __shared__ char smem[];
    float*    S    = (float*)smem;                    // 4*3140 f32 = 50240 B
    unsigned* hist = (unsigned*)(smem + 50240);       // 4*1024 u32 (u16-packed)
    unsigned* cand = (unsigned*)(smem + 50240);       // 8*896 u32
    float*    red  = (float*)(smem + 50240);          // 16*128 f32
    AttnMisc* M    = (AttnMisc*)(smem + 50240 + 28672);

    int tid = threadIdx.x, lane = tid & 63, wid = tid >> 6;
    int bh = blockIdx.y, n0 = blockIdx.x * ROWS;
    size_t bhN = (size_t)bh * N_;

    if (tid < PROBS) M->cntM[tid] = 0u;
    if (tid == 0) { M->pp[0] = p1p[0]; M->pp[1] = p2p[0]; }
    for (int i = tid; i < HISTW; i += 1024) hist[i] = 0u;
    __syncthreads();

    // ---- P0: scores + rowmax + 11-bit packed histogram ----
    const float* qrow = qh + (bhN + n0) * D_;
    float lmax[ROWS];
#pragma unroll
    for (int r = 0; r < ROWS; ++r) lmax[r] = -3.4e38f;
    for (int i = 0; i < 4; ++i) {
        int j = tid + (i << 10);
        if (j < N_) {
            const float4* kp = (const float4*)(kh + (bhN + j) * D_);
            float4 k4[8];
#pragma unroll
            for (int q = 0; q < 8; ++q) k4[q] = kp[q];
#pragma unroll
            for (int r = 0; r < ROWS; ++r) {
                const float4* qp = (const float4*)(qrow + r * D_);
                float s = 0.f;
#pragma unroll
                for (int q = 0; q < 8; ++q) {
                    float4 q4 = qp[q];
                    s += q4.x * k4[q].x + q4.y * k4[q].y + q4.z * k4[q].z + q4.w * k4[q].w;
                }
                S[r * SROW + j] = s;
                lmax[r] = fmaxf(lmax[r], s);
                unsigned bin = ordf(s) >> 21;
                atomicAdd(&hist[(r << 10) + (bin >> 1)], 1u << ((bin & 1) << 4));
            }
        }
    }
#pragma unroll
    for (int r = 0; r < ROWS; ++r) {
        float v = lmax[r];
#pragma unroll
        for (int d = 32; d; d >>= 1) v = fmaxf(v, __shfl_down(v, d, 64));
        if (lane == 0) M->wred[wid * 16 + r] = v;
    }
    __syncthreads();

    // ---- rowmax finalize + histogram search (wave w -> problem w, w<8) ----
    if (tid < ROWS) {
        float mm = -3.4e38f;
        for (int w = 0; w < 16; ++w) mm = fmaxf(mm, M->wred[w * 16 + tid]);
        M->rowmax[tid] = mm;
    }
    if (wid < PROBS) {
        int prob = wid;
        int r = prob >> 1;
        int k = (prob & 1) ? K2CNT : K1CNT;
        const unsigned* hrow = hist + (r << 10) + (lane << 4);
        uint4 ha = *(const uint4*)(hrow + 0);
        uint4 hb = *(const uint4*)(hrow + 4);
        uint4 hc = *(const uint4*)(hrow + 8);
        uint4 hd = *(const uint4*)(hrow + 12);
        unsigned hh[16] = { ha.x, ha.y, ha.z, ha.w, hb.x, hb.y, hb.z, hb.w,
                            hc.x, hc.y, hc.z, hc.w, hd.x, hd.y, hd.z, hd.w };
        unsigned usum = 0;
#pragma unroll
        for (int t = 0; t < 16; ++t) usum += hh[t];
        int ltot = (int)((usum & 0xFFFFu) + (usum >> 16));   // row total <= 3136: no carry
        int s = ltot;
#pragma unroll
        for (int d = 1; d < 64; d <<= 1) {
            int o = __shfl_down(s, d, 64);
            if (lane + d < 64) s += o;
        }
        int after = s - ltot;            // counts in higher lanes' (larger) bins
        if (after < k && after + ltot >= k) {   // crossing lane (unique)
            int g = after, b0 = -1, selr = 0;
#pragma unroll
            for (int m = 31; m >= 0; --m) {
                unsigned w = hh[m >> 1];
                int cm = (m & 1) ? (int)(w >> 16) : (int)(w & 0xFFFFu);
                g += cm;
                if (b0 < 0 && g >= k) { b0 = (lane << 5) + m; selr = k - (g - cm); }
            }
            M->thrBin[prob] = (unsigned)b0;
            M->selrM[prob] = selr;
        }
    }
    __syncthreads();

    // ---- P1: gather candidates sharing the selected 11-bit prefix ----
    unsigned tb[PROBS];
#pragma unroll
    for (int p = 0; p < PROBS; ++p) tb[p] = M->thrBin[p];
    {
        int j4 = tid << 2;
        if (j4 < N_) {                       // 784 active threads (3136 = 784*4)
#pragma unroll
            for (int r = 0; r < ROWS; ++r) {
                float4 sv = *(const float4*)&S[r * SROW + j4];
                float sa[4] = { sv.x, sv.y, sv.z, sv.w };
#pragma unroll
                for (int t = 0; t < 4; ++t) {
                    unsigned uu = ordf(sa[t]);
                    unsigned bin = uu >> 21;
                    if (bin == tb[2 * r]) {
                        unsigned idx = atomicAdd(&M->cntM[2 * r], 1u);
                        if (idx < CAP) cand[(2 * r) * CAP + idx] = uu;
                    }
                    if (bin == tb[2 * r + 1]) {
                        unsigned idx = atomicAdd(&M->cntM[2 * r + 1], 1u);
                        if (idx < CAP) cand[(2 * r + 1) * CAP + idx] = uu;
                    }
                }
            }
        }
    }
    __syncthreads();

    // ---- refine: ballot-radix over remaining 21 bits, wave w -> problem w ----
    if (wid < PROBS) {
        int prob = wid;
        int cnt = (int)M->cntM[prob]; if (cnt > CAP) cnt = CAP;
        unsigned kk = (unsigned)M->selrM[prob];
        unsigned bin = M->thrBin[prob];
        const unsigned* cp = cand + prob * CAP;
        unsigned bits = 0;
        if (cnt <= 64)       REFINE_BODY(1)
        else if (cnt <= 192) REFINE_BODY(3)
        else                 REFINE_BODY(15)
        if (lane == 0) M->thrU[prob] = (bin << 21) | bits;
    }
    __syncthreads();

    // ---- masked exp sums + signed markers written in place (vectorized) ----
    unsigned t1r[ROWS], t2r[ROWS]; float rm[ROWS];
#pragma unroll
    for (int r = 0; r < ROWS; ++r) {
        t1r[r] = M->thrU[2 * r];
        t2r[r] = M->thrU[2 * r + 1];
        rm[r] = M->rowmax[r];
    }
    float ls1a[ROWS] = {}, ls2a[ROWS] = {};
    {
        int j4 = tid << 2;
        if (j4 < N_) {
#pragma unroll
            for (int r = 0; r < ROWS; ++r) {
                float4 sv = *(const float4*)&S[r * SROW + j4];
                float sa[4] = { sv.x, sv.y, sv.z, sv.w };
#pragma unroll
                for (int t = 0; t < 4; ++t) {
                    float a = sa[t];
                    unsigned uu = ordf(a);
                    float outv = 0.f;
                    if (uu >= t1r[r]) {
                        float w = __expf(a - rm[r]);
                        ls1a[r] += w;
                        if (uu >= t2r[r]) { ls2a[r] += w; outv = w; }
                        else outv = -w;
                    }
                    sa[t] = outv;
                }
                *(float4*)&S[r * SROW + j4] = make_float4(sa[0], sa[1], sa[2], sa[3]);
            }
        }
    }
#pragma unroll
    for (int r = 0; r < ROWS; ++r) {
        float a1 = ls1a[r], a2 = ls2a[r];
#pragma unroll
        for (int d = 32; d; d >>= 1) { a1 += __shfl_down(a1, d, 64); a2 += __shfl_down(a2, d, 64); }
        if (lane == 0) { M->wred[wid * 16 + r * 2] = a1; M->wred[wid * 16 + r * 2 + 1] = a2; }
    }
    __syncthreads();
    if (tid < PROBS) {
        float ssum = 0.f;
        for (int w = 0; w < 16; ++w) ssum += M->wred[w * 16 + tid];
        M->coef[tid] = ((tid & 1) ? M->pp[1] : M->pp[0]) / ssum;
    }
    __syncthreads();

    // ---- pre-transform: signed markers -> final AV coefficients (in place) ----
    {
        float c1v[ROWS], c12v[ROWS];
#pragma unroll
        for (int r = 0; r < ROWS; ++r) {
            float a = M->coef[2 * r], b2 = M->coef[2 * r + 1];
            c1v[r] = a; c12v[r] = a + b2;
        }
        int j4 = tid << 2;
        if (j4 < N_) {
#pragma unroll
            for (int r = 0; r < ROWS; ++r) {
                float4 sv = *(const float4*)&S[r * SROW + j4];
                sv.x = (sv.x > 0.f) ? sv.x * c12v[r] : -sv.x * c1v[r];
                sv.y = (sv.y > 0.f) ? sv.y * c12v[r] : -sv.y * c1v[r];
                sv.z = (sv.z > 0.f) ? sv.z * c12v[r] : -sv.z * c1v[r];
                sv.w = (sv.w > 0.f) ? sv.w * c12v[r] : -sv.w * c1v[r];
                *(float4*)&S[r * SROW + j4] = sv;
            }
        }
    }
    __syncthreads();

    // ---- AV: 32-j groups, V direct from global (L2-resident), reg accumulate ----
    int jj4 = lane >> 3, dq = lane & 7;
    float4 acc[ROWS];
#pragma unroll
    for (int r = 0; r < ROWS; ++r) acc[r] = make_float4(0.f, 0.f, 0.f, 0.f);
    const float* vbase = vh + bhN * D_ + (dq << 2);
    for (int g = wid; g < 98; g += 16) {        // 98 groups of 32 j (3136 = 98*32)
        int jb = (g << 5) + (jj4 << 2);
        float4 v0 = *(const float4*)(vbase + (size_t)(jb + 0) * D_);
        float4 v1 = *(const float4*)(vbase + (size_t)(jb + 1) * D_);
        float4 v2 = *(const float4*)(vbase + (size_t)(jb + 2) * D_);
        float4 v3 = *(const float4*)(vbase + (size_t)(jb + 3) * D_);
#pragma unroll
        for (int r = 0; r < ROWS; ++r) {
            float4 s4 = *(const float4*)&S[r * SROW + jb];
            acc[r].x += s4.x * v0.x + s4.y * v1.x + s4.z * v2.x + s4.w * v3.x;
            acc[r].y += s4.x * v0.y + s4.y * v1.y + s4.z * v2.y + s4.w * v3.y;
            acc[r].z += s4.x * v0.z + s4.y * v1.z + s4.z * v2.z + s4.w * v3.z;
            acc[r].w += s4.x * v0.w + s4.y * v1.w + s4.z * v2.w + s4.w * v3.w;
        }
    }
    // reduce over jj4 groups (xor 8,16,32)
#pragma unroll
    for (int m = 8; m < 64; m <<= 1) {
#pragma unroll
        for (int r = 0; r < ROWS; ++r) {
            acc[r].x += __shfl_xor(acc[r].x, m, 64);
            acc[r].y += __shfl_xor(acc[r].y, m, 64);
            acc[r].z += __shfl_xor(acc[r].z, m, 64);
            acc[r].w += __shfl_xor(acc[r].w, m, 64);
        }
    }
    if (lane < 8) {
#pragma unroll
        for (int r = 0; r < ROWS; ++r)
            *(float4*)&red[(wid << 7) + (r << 5) + (lane << 2)] = acc[r];
    }
    __syncthreads();
    if (tid < 32 * ROWS) {
        float o = 0.f;
#pragma unroll
        for (int w = 0; w < 16; ++w) o += red[(w << 7) + tid];
        int r = tid >> 5, d = tid & 31;
        int b = bh >> 3, h = bh & 7;
        aoT[((size_t)(b * C_ + h * 32 + d)) * N_ + n0 + r] = o;
    }
}

static const int ATTN_SMEM = 50240 + 28672 + (int)sizeof(AttnMisc);

extern "C" void kernel_launch(void* const* d_in, const int* in_sizes, int n_in,
                              void* d_out, int out_size, void* d_ws, size_t ws_size,
                              hipStream_t stream)
{
    (void)in_sizes; (void)n_in; (void)out_size; (void)ws_size;
    const float* x    = (const float*)d_in[0];
    const float* y    = (const float*)d_in[1];
    const float* q_w  = (const float*)d_in[2];
    const float* q_b  = (const float*)d_in[3];
    const float* kv_w = (const float*)d_in[4];
    const float* kv_b = (const float*)d_in[5];
    const float* p_w  = (const float*)d_in[6];
    const float* p_b  = (const float*)d_in[7];
    const float* lnw  = (const float*)d_in[8];
    const float* lnb  = (const float*)d_in[9];
    const float* a1p  = (const float*)d_in[10];
    const float* a2p  = (const float*)d_in[11];
    float* out = (float*)d_out;

    float* ws = (float*)d_ws;
    const size_t PLANE = (size_t)B_ * C_ * N_;
    float* yp  = ws;
    float* yfT = ws + PLANE;
    float* qh_ = ws + 2 * PLANE;
    float* kh_ = ws + 3 * PLANE;
    float* vh_ = ws + 4 * PLANE;
    float* aoT = ws + 5 * PLANE;

    pool_kernel<<<dim3((unsigned)(PLANE / 256)), 256, 0, stream>>>(y, yp);
    ln_kernel<<<dim3(B_ * N_), 256, 0, stream>>>(yp, lnw, lnb, yfT);
    gemm_qkv<<<dim3(98, 4), 256, 0, stream>>>(x, q_w, q_b, qh_, nullptr, 0.17677669529663687f);
    gemm_qkv<<<dim3(98, 8), 256, 0, stream>>>(yfT, kv_w, kv_b, kh_, vh_, 1.0f);
    hipFuncSetAttribute(reinterpret_cast<const void*>(attn_kernel),
                        hipFuncAttributeMaxDynamicSharedMemorySize, ATTN_SMEM);
    attn_kernel<<<dim3(N_ / ROWS, B_ * NH_), 1024, ATTN_SMEM, stream>>>(qh_, kh_, vh_, a1p, a2p, aoT);
    gemm_proj<<<dim3(98, 4), 256, 0, stream>>>(aoT, p_w, p_b, out);
}

// Round 3
// 1012.652 us; speedup vs baseline: 1.6642x; 1.1837x over previous
//
#include <hip/hip_runtime.h>

#define B_    2
#define C_    256
#define HW_   56
#define N_    3136     // 56*56
#define NH_   8
#define D_    32
#define K1CNT 1568     // N_/2
#define K2CNT 1045     // N_//3
#define LN_EPS 1e-5f
#define SROW  3140     // padded score row; 3140%32==4
#define ROWS  4        // q-rows per block
#define PROBS 8        // ROWS * 2 top-k problems
#define HISTW 4096     // ROWS * 1024 words (2048 bins, u16-packed pairs)
#define CAP   896      // candidate capacity per problem
#define RM    8.0f     // row-uniform exp shift (softmax is shift-invariant; |s| << 8)

// LDS: S 50240 | hist 16384 / cand 28672 / red 8192 (overlaid) | misc ~296
// total ~79.2 KB <= 81920  ->  2 blocks/CU (32 waves = CU wave cap)

// ---------------- helpers ----------------
__device__ inline unsigned ordf(float f) {
    unsigned u = __float_as_uint(f);
    return u ^ (((unsigned)((int)u >> 31)) | 0x80000000u);
}

// full-wave sum: xor-butterfly via ds_swizzle (lanes 0-31 halves) + cross-32 shfl
__device__ inline float redsum64(float v) {
    v += __int_as_float(__builtin_amdgcn_ds_swizzle(__float_as_int(v), 0x041F)); // xor 1
    v += __int_as_float(__builtin_amdgcn_ds_swizzle(__float_as_int(v), 0x081F)); // xor 2
    v += __int_as_float(__builtin_amdgcn_ds_swizzle(__float_as_int(v), 0x101F)); // xor 4
    v += __int_as_float(__builtin_amdgcn_ds_swizzle(__float_as_int(v), 0x201F)); // xor 8
    v += __int_as_float(__builtin_amdgcn_ds_swizzle(__float_as_int(v), 0x401F)); // xor 16
    v += __shfl_xor(v, 32, 64);
    return v;
}

// sum over jj4 groups (xor 8,16,32)
__device__ inline float avred(float v) {
    v += __int_as_float(__builtin_amdgcn_ds_swizzle(__float_as_int(v), 0x201F)); // xor 8
    v += __int_as_float(__builtin_amdgcn_ds_swizzle(__float_as_int(v), 0x401F)); // xor 16
    v += __shfl_xor(v, 32, 64);
    return v;
}

// ---------------- pooling (3 avg pools summed, zero-pad, divisor k*k) -------
__global__ void pool_kernel(const float* __restrict__ y, float* __restrict__ yp)
{
    int gid = blockIdx.x * 256 + threadIdx.x;
    int n  = gid % N_;
    int bc = gid / N_;
    const float* src = y + (size_t)bc * N_;
    int x0 = n % HW_, y0 = n / HW_;
    float acc = 0.f;
#pragma unroll
    for (int dy = -3; dy <= 3; ++dy) {
        int yy = y0 + dy;
        if ((unsigned)yy >= HW_) continue;
#pragma unroll
        for (int dx = -3; dx <= 3; ++dx) {
            int xx = x0 + dx;
            if ((unsigned)xx >= HW_) continue;
            float w = 1.f / 49.f;
            if (dy >= -2 && dy <= 2 && dx >= -2 && dx <= 2) w += 1.f / 25.f;
            if (dy >= -1 && dy <= 1 && dx >= -1 && dx <= 1) w += 1.f / 9.f;
            acc += w * src[yy * HW_ + xx];
        }
    }
    yp[gid] = acc;
}

// ---------------- layernorm over C, writes transposed [B,C,N] ---------------
__global__ void ln_kernel(const float* __restrict__ yp, const float* __restrict__ lnw,
                          const float* __restrict__ lnb, float* __restrict__ yfT)
{
    __shared__ float wr[8];
    __shared__ float stats[2];
    int idx = blockIdx.x;
    int b = idx / N_, n = idx % N_;
    int c = threadIdx.x;
    size_t off = ((size_t)b * C_ + c) * N_ + n;
    float v = yp[off];
    float s = v, q = v * v;
    int lane = threadIdx.x & 63, wid = threadIdx.x >> 6;
#pragma unroll
    for (int d = 32; d; d >>= 1) { s += __shfl_down(s, d, 64); q += __shfl_down(q, d, 64); }
    if (lane == 0) { wr[wid] = s; wr[4 + wid] = q; }
    __syncthreads();
    if (threadIdx.x == 0) {
        float ts = wr[0] + wr[1] + wr[2] + wr[3];
        float tq = wr[4] + wr[5] + wr[6] + wr[7];
        float mu = ts * (1.f / C_);
        float var = tq * (1.f / C_) - mu * mu;
        stats[0] = mu; stats[1] = rsqrtf(var + LN_EPS);
    }
    __syncthreads();
    yfT[off] = (v - stats[0]) * stats[1] * lnw[c] + lnb[c];
}

// ---------------- GEMM: out = A(AT layout [B,C,N]) @ W[O,K]^T + bias --------
__global__ __launch_bounds__(256) void gemm_qkv(
    const float* __restrict__ A, const float* __restrict__ W,
    const float* __restrict__ bias, float* __restrict__ dst0,
    float* __restrict__ dst1, float scale)
{
    __shared__ float As[16][64];
    __shared__ float Ws[16][68];
    int tid = threadIdx.x;
    int m0 = blockIdx.x * 64;
    int b = m0 / N_, n0 = m0 % N_;
    int o0 = blockIdx.y * 64;
    const float* Ab = A + (size_t)b * C_ * N_;
    float acc[4][4] = {};
    int la_k = tid >> 4;
    int la_m = (tid & 15) * 4;
    int lw_o = tid >> 2;
    int lw_k = (tid & 3) * 4;
    int u  = tid & 15;
    int v_ = tid >> 4;
    for (int kt = 0; kt < 16; ++kt) {
        int k0 = kt * 16;
        float4 av = *(const float4*)&Ab[(size_t)(k0 + la_k) * N_ + n0 + la_m];
        float4 wv = *(const float4*)&W[(size_t)(o0 + lw_o) * C_ + k0 + lw_k];
        __syncthreads();
        *(float4*)&As[la_k][la_m] = av;
        Ws[lw_k + 0][lw_o] = wv.x; Ws[lw_k + 1][lw_o] = wv.y;
        Ws[lw_k + 2][lw_o] = wv.z; Ws[lw_k + 3][lw_o] = wv.w;
        __syncthreads();
#pragma unroll
        for (int k = 0; k < 16; ++k) {
            float4 wf = *(const float4*)&Ws[k][u * 4];
            float a0 = As[k][v_], a1 = As[k][v_ + 16], a2 = As[k][v_ + 32], a3 = As[k][v_ + 48];
            acc[0][0] += wf.x * a0; acc[0][1] += wf.x * a1; acc[0][2] += wf.x * a2; acc[0][3] += wf.x * a3;
            acc[1][0] += wf.y * a0; acc[1][1] += wf.y * a1; acc[1][2] += wf.y * a2; acc[1][3] += wf.y * a3;
            acc[2][0] += wf.z * a0; acc[2][1] += wf.z * a1; acc[2][2] += wf.z * a2; acc[2][3] += wf.z * a3;
            acc[3][0] += wf.w * a0; acc[3][1] += wf.w * a1; acc[3][2] += wf.w * a2; acc[3][3] += wf.w * a3;
        }
    }
    int oc = o0 + u * 4;
    float b0v = bias[oc], b1v = bias[oc + 1], b2v = bias[oc + 2], b3v = bias[oc + 3];
    float* dst = dst0; int c2 = oc;
    if (dst1 && oc >= C_) { dst = dst1; c2 = oc - C_; }
    int h = c2 >> 5, d0 = c2 & 31;
    size_t base = ((size_t)b * NH_ + h) * N_ * D_;
#pragma unroll
    for (int j = 0; j < 4; ++j) {
        int n = n0 + v_ + j * 16;
        float4 val;
        val.x = (acc[0][j] + b0v) * scale;
        val.y = (acc[1][j] + b1v) * scale;
        val.z = (acc[2][j] + b2v) * scale;
        val.w = (acc[3][j] + b3v) * scale;
        *(float4*)&dst[base + (size_t)n * D_ + d0] = val;
    }
}

__global__ __launch_bounds__(256) void gemm_proj(
    const float* __restrict__ A, const float* __restrict__ W,
    const float* __restrict__ bias, float* __restrict__ out)
{
    __shared__ float As[16][64];
    __shared__ float Ws[16][68];
    int tid = threadIdx.x;
    int m0 = blockIdx.x * 64;
    int b = m0 / N_, n0 = m0 % N_;
    int o0 = blockIdx.y * 64;
    const float* Ab = A + (size_t)b * C_ * N_;
    float acc[4][4] = {};
    int la_k = tid >> 4;
    int la_m = (tid & 15) * 4;
    int lw_o = tid >> 2;
    int lw_k = (tid & 3) * 4;
    int u  = tid & 15;
    int v_ = tid >> 4;
    for (int kt = 0; kt < 16; ++kt) {
        int k0 = kt * 16;
        float4 av = *(const float4*)&Ab[(size_t)(k0 + la_k) * N_ + n0 + la_m];
        float4 wv = *(const float4*)&W[(size_t)(o0 + lw_o) * C_ + k0 + lw_k];
        __syncthreads();
        *(float4*)&As[la_k][la_m] = av;
        Ws[lw_k + 0][lw_o] = wv.x; Ws[lw_k + 1][lw_o] = wv.y;
        Ws[lw_k + 2][lw_o] = wv.z; Ws[lw_k + 3][lw_o] = wv.w;
        __syncthreads();
#pragma unroll
        for (int k = 0; k < 16; ++k) {
            float4 af = *(const float4*)&As[k][u * 4];
            float w0 = Ws[k][v_], w1 = Ws[k][v_ + 16], w2 = Ws[k][v_ + 32], w3 = Ws[k][v_ + 48];
            acc[0][0] += w0 * af.x; acc[0][1] += w0 * af.y; acc[0][2] += w0 * af.z; acc[0][3] += w0 * af.w;
            acc[1][0] += w1 * af.x; acc[1][1] += w1 * af.y; acc[1][2] += w1 * af.z; acc[1][3] += w1 * af.w;
            acc[2][0] += w2 * af.x; acc[2][1] += w2 * af.y; acc[2][2] += w2 * af.z; acc[2][3] += w2 * af.w;
            acc[3][0] += w3 * af.x; acc[3][1] += w3 * af.y; acc[3][2] += w3 * af.z; acc[3][3] += w3 * af.w;
        }
    }
#pragma unroll
    for (int i = 0; i < 4; ++i) {
        int o = o0 + v_ + i * 16;
        float bb = bias[o];
        float4 val;
        val.x = acc[i][0] + bb; val.y = acc[i][1] + bb;
        val.z = acc[i][2] + bb; val.w = acc[i][3] + bb;
        *(float4*)&out[((size_t)b * C_ + o) * N_ + n0 + u * 4] = val;
    }
}

// ---------------- fused attention (1024 threads, 16 waves, 4 q-rows) --------
struct AttnMisc {
    unsigned thrBin[PROBS];
    int selrM[PROBS];
    unsigned thrU[PROBS];
    unsigned cntM[PROBS];
    float coef[PROBS];
    float pp[2];
    float wred[32];      // 16 waves x {dsum1, dsum2} of its row
};

// radix refine (bits) + boundary exp-sum over candidate values already in regs
#define REFINE_BSUM(NV)                                                    \
    {                                                                      \
        unsigned vv[NV]; unsigned aok = 0;                                 \
        _Pragma("unroll")                                                  \
        for (int t = 0; t < NV; ++t) {                                     \
            int idx = lane + (t << 6);                                     \
            bool ok = idx < cnt;                                           \
            vv[t] = ok ? cp[idx] : 0u;                                     \
            if (ok) aok |= 1u << t;                                        \
        }                                                                  \
        unsigned act = aok;                                                \
        for (int b = 20; b >= 0; --b) {                                    \
            unsigned msk = 0, c = 0;                                       \
            _Pragma("unroll")                                              \
            for (int t = 0; t < NV; ++t) {                                 \
                bool p = ((act >> t) & 1u) && ((vv[t] >> b) & 1u);         \
                c += (unsigned)__popcll(__ballot(p));                      \
                if (p) msk |= 1u << t;                                     \
            }                                                              \
            if (c >= kk) { act = msk; bits |= 1u << b; }                   \
            else { kk -= c; act &= ~msk; }                                 \
        }                                                                  \
        unsigned thr = (bin << 21) | bits;                                 \
        _Pragma("unroll")                                                  \
        for (int t = 0; t < NV; ++t) {                                     \
            if (((aok >> t) & 1u) && vv[t] >= thr) {                       \
                unsigned uo = vv[t] ^ (~((unsigned)((int)vv[t] >> 31)) | 0x80000000u); \
                bsum += __expf(__uint_as_float(uo) - RM);                  \
            }                                                              \
        }                                                                  \
    }

__global__ __launch_bounds__(1024, 8) void attn_kernel(
    const float* __restrict__ qh, const float* __restrict__ kh, const float* __restrict__ vh,
    const float* __restrict__ p1p, const float* __restrict__ p2p,
    float* __restrict__ aoT)
{
    extern __shared__ char smem[];
    float*    S    = (float*)smem;                    // 4*3140 f32 = 50240 B
    unsigned* hist = (unsigned*)(smem + 50240);       // 4*1024 u32 (u16-packed)
    unsigned* cand = (unsigned*)(smem + 50240);       // 8*896 u32
    float*    red  = (float*)(smem + 50240);          // 16*128 f32
    AttnMisc* M    = (AttnMisc*)(smem + 50240 + 28672);

    int tid = threadIdx.x, lane = tid & 63, wid = tid >> 6;
    int bh = blockIdx.y, n0 = blockIdx.x * ROWS;
    size_t bhN = (size_t)bh * N_;

    if (tid < PROBS) M->cntM[tid] = 0u;
    if (tid == 0) { M->pp[0] = p1p[0]; M->pp[1] = p2p[0]; }
    for (int i = tid; i < HISTW; i += 1024) hist[i] = 0u;
    __syncthreads();

    // ---- P0: scores + 11-bit packed histogram (no rowmax needed: RM const) ----
    const float* qrow = qh + (bhN + n0) * D_;
    for (int i = 0; i < 4; ++i) {
        int j = tid + (i << 10);
        if (j < N_) {
            const float4* kp = (const float4*)(kh + (bhN + j) * D_);
            float4 k4[8];
#pragma unroll
            for (int q = 0; q < 8; ++q) k4[q] = kp[q];
#pragma unroll
            for (int r = 0; r < ROWS; ++r) {
                const float4* qp = (const float4*)(qrow + r * D_);
                float s = 0.f;
#pragma unroll
                for (int q = 0; q < 8; ++q) {
                    float4 q4 = qp[q];
                    s += q4.x * k4[q].x + q4.y * k4[q].y + q4.z * k4[q].z + q4.w * k4[q].w;
                }
                S[r * SROW + j] = s;
                unsigned bin = ordf(s) >> 21;
                atomicAdd(&hist[(r << 10) + (bin >> 1)], 1u << ((bin & 1) << 4));
            }
        }
    }
    __syncthreads();

    // ---- histogram search (wave w -> problem w, w<8) ----
    if (wid < PROBS) {
        int prob = wid;
        int r = prob >> 1;
        int k = (prob & 1) ? K2CNT : K1CNT;
        const unsigned* hrow = hist + (r << 10) + (lane << 4);
        uint4 ha = *(const uint4*)(hrow + 0);
        uint4 hb = *(const uint4*)(hrow + 4);
        uint4 hc = *(const uint4*)(hrow + 8);
        uint4 hd = *(const uint4*)(hrow + 12);
        unsigned hh[16] = { ha.x, ha.y, ha.z, ha.w, hb.x, hb.y, hb.z, hb.w,
                            hc.x, hc.y, hc.z, hc.w, hd.x, hd.y, hd.z, hd.w };
        unsigned usum = 0;
#pragma unroll
        for (int t = 0; t < 16; ++t) usum += hh[t];
        int ltot = (int)((usum & 0xFFFFu) + (usum >> 16));   // row total <= 3136: no carry
        int s = ltot;
#pragma unroll
        for (int d = 1; d < 64; d <<= 1) {
            int o = __shfl_down(s, d, 64);
            if (lane + d < 64) s += o;
        }
        int after = s - ltot;            // counts in higher lanes' (larger) bins
        if (after < k && after + ltot >= k) {   // crossing lane (unique)
            int g = after, b0 = -1, selr = 0;
#pragma unroll
            for (int m = 31; m >= 0; --m) {
                unsigned w = hh[m >> 1];
                int cm = (m & 1) ? (int)(w >> 16) : (int)(w & 0xFFFFu);
                g += cm;
                if (b0 < 0 && g >= k) { b0 = (lane << 5) + m; selr = k - (g - cm); }
            }
            M->thrBin[prob] = (unsigned)b0;
            M->selrM[prob] = selr;
        }
    }
    __syncthreads();

    // ---- P1: gather candidates + definite exp-sums (row-per-wave-group) ----
    {
        int row = wid >> 2;
        int sub = ((wid & 3) << 6) | lane;      // 0..255 within row group
        unsigned tb1 = M->thrBin[2 * row], tb2 = M->thrBin[2 * row + 1];
        int p1 = 2 * row, p2 = 2 * row + 1;
        float ds1 = 0.f, ds2 = 0.f;
        const float* Srow = S + row * SROW;
#pragma unroll
        for (int i = 0; i < 4; ++i) {
            int q = sub + (i << 8);
            if (q < 784) {                       // 784 quads * 4 = 3136
                float4 sv = *(const float4*)&Srow[q << 2];
                float sa[4] = { sv.x, sv.y, sv.z, sv.w };
#pragma unroll
                for (int t = 0; t < 4; ++t) {
                    unsigned u = ordf(sa[t]);
                    unsigned bin = u >> 21;
                    if (bin > tb1) {
                        float w = __expf(sa[t] - RM);
                        ds1 += w;
                        if (bin > tb2) ds2 += w;
                    }
                    if (bin == tb1) {
                        unsigned ix = atomicAdd(&M->cntM[p1], 1u);
                        if (ix < CAP) cand[p1 * CAP + ix] = u;
                    }
                    if (bin == tb2) {
                        unsigned ix = atomicAdd(&M->cntM[p2], 1u);
                        if (ix < CAP) cand[p2 * CAP + ix] = u;
                    }
                }
            }
        }
        ds1 = redsum64(ds1);
        ds2 = redsum64(ds2);
        if (lane == 0) { M->wred[wid * 2] = ds1; M->wred[wid * 2 + 1] = ds2; }
    }
    __syncthreads();

    // ---- refine (21-bit ballot-radix) + boundary sums + coef, wave w -> prob w ----
    if (wid < PROBS) {
        int prob = wid;
        int cnt = (int)M->cntM[prob]; if (cnt > CAP) cnt = CAP;
        unsigned kk = (unsigned)M->selrM[prob];
        unsigned bin = M->thrBin[prob];
        const unsigned* cp = cand + prob * CAP;
        unsigned bits = 0;
        float bsum = 0.f;
        if (cnt <= 64)       REFINE_BSUM(1)
        else if (cnt <= 192) REFINE_BSUM(3)
        else                 REFINE_BSUM(15)
        bsum = redsum64(bsum);
        if (lane == 0) {
            M->thrU[prob] = (bin << 21) | bits;
            int rw = (prob >> 1) << 2;           // first wave of this row's group
            float denom = bsum
                + M->wred[(rw + 0) * 2 + (prob & 1)]
                + M->wred[(rw + 1) * 2 + (prob & 1)]
                + M->wred[(rw + 2) * 2 + (prob & 1)]
                + M->wred[(rw + 3) * 2 + (prob & 1)];
            M->coef[prob] = M->pp[prob & 1] / denom;
        }
    }
    __syncthreads();

    // ---- transform: raw scores -> final AV coefficients (row-per-wave-group) ----
    {
        int row = wid >> 2;
        int sub = ((wid & 3) << 6) | lane;
        unsigned u1 = M->thrU[2 * row], u2 = M->thrU[2 * row + 1];
        float c1 = M->coef[2 * row];
        float c12 = c1 + M->coef[2 * row + 1];
        float* Srow = S + row * SROW;
#pragma unroll
        for (int i = 0; i < 4; ++i) {
            int q = sub + (i << 8);
            if (q < 784) {
                float4 sv = *(const float4*)&Srow[q << 2];
                float sa[4] = { sv.x, sv.y, sv.z, sv.w };
#pragma unroll
                for (int t = 0; t < 4; ++t) {
                    float a = sa[t];
                    unsigned u = ordf(a);
                    float c = 0.f;
                    if (u >= u1) {
                        float w = __expf(a - RM);
                        c = (u >= u2) ? w * c12 : w * c1;
                    }
                    sa[t] = c;
                }
                *(float4*)&Srow[q << 2] = make_float4(sa[0], sa[1], sa[2], sa[3]);
            }
        }
    }
    __syncthreads();

    // ---- AV: 32-j groups, V direct from global (L2-resident), reg accumulate ----
    int jj4 = lane >> 3, dq = lane & 7;
    float4 acc[ROWS];
#pragma unroll
    for (int r = 0; r < ROWS; ++r) acc[r] = make_float4(0.f, 0.f, 0.f, 0.f);
    const float* vbase = vh + bhN * D_ + (dq << 2);
    for (int g = wid; g < 98; g += 16) {        // 98 groups of 32 j
        int jb = (g << 5) + (jj4 << 2);
        float4 v0 = *(const float4*)(vbase + (size_t)(jb + 0) * D_);
        float4 v1 = *(const float4*)(vbase + (size_t)(jb + 1) * D_);
        float4 v2 = *(const float4*)(vbase + (size_t)(jb + 2) * D_);
        float4 v3 = *(const float4*)(vbase + (size_t)(jb + 3) * D_);
#pragma unroll
        for (int r = 0; r < ROWS; ++r) {
            float4 s4 = *(const float4*)&S[r * SROW + jb];
            acc[r].x += s4.x * v0.x + s4.y * v1.x + s4.z * v2.x + s4.w * v3.x;
            acc[r].y += s4.x * v0.y + s4.y * v1.y + s4.z * v2.y + s4.w * v3.y;
            acc[r].z += s4.x * v0.z + s4.y * v1.z + s4.z * v2.z + s4.w * v3.z;
            acc[r].w += s4.x * v0.w + s4.y * v1.w + s4.z * v2.w + s4.w * v3.w;
        }
    }
#pragma unroll
    for (int r = 0; r < ROWS; ++r) {
        acc[r].x = avred(acc[r].x);
        acc[r].y = avred(acc[r].y);
        acc[r].z = avred(acc[r].z);
        acc[r].w = avred(acc[r].w);
    }
    if (lane < 8) {
#pragma unroll
        for (int r = 0; r < ROWS; ++r)
            *(float4*)&red[(wid << 7) + (r << 5) + (lane << 2)] = acc[r];
    }
    __syncthreads();
    if (tid < 32 * ROWS) {
        float o = 0.f;
#pragma unroll
        for (int w = 0; w < 16; ++w) o += red[(w << 7) + tid];
        int r = tid >> 5, d = tid & 31;
        int b = bh >> 3, h = bh & 7;
        aoT[((size_t)(b * C_ + h * 32 + d)) * N_ + n0 + r] = o;
    }
}

static const int ATTN_SMEM = 50240 + 28672 + (int)sizeof(AttnMisc);

extern "C" void kernel_launch(void* const* d_in, const int* in_sizes, int n_in,
                              void* d_out, int out_size, void* d_ws, size_t ws_size,
                              hipStream_t stream)
{
    (void)in_sizes; (void)n_in; (void)out_size; (void)ws_size;
    const float* x    = (const float*)d_in[0];
    const float* y    = (const float*)d_in[1];
    const float* q_w  = (const float*)d_in[2];
    const float* q_b  = (const float*)d_in[3];
    const float* kv_w = (const float*)d_in[4];
    const float* kv_b = (const float*)d_in[5];
    const float* p_w  = (const float*)d_in[6];
    const float* p_b  = (const float*)d_in[7];
    const float* lnw  = (const float*)d_in[8];
    const float* lnb  = (const float*)d_in[9];
    const float* a1p  = (const float*)d_in[10];
    const float* a2p  = (const float*)d_in[11];
    float* out = (float*)d_out;

    float* ws = (float*)d_ws;
    const size_t PLANE = (size_t)B_ * C_ * N_;
    float* yp  = ws;
    float* yfT = ws + PLANE;
    float* qh_ = ws + 2 * PLANE;
    float* kh_ = ws + 3 * PLANE;
    float* vh_ = ws + 4 * PLANE;
    float* aoT = ws + 5 * PLANE;

    pool_kernel<<<dim3((unsigned)(PLANE / 256)), 256, 0, stream>>>(y, yp);
    ln_kernel<<<dim3(B_ * N_), 256, 0, stream>>>(yp, lnw, lnb, yfT);
    gemm_qkv<<<dim3(98, 4), 256, 0, stream>>>(x, q_w, q_b, qh_, nullptr, 0.17677669529663687f);
    gemm_qkv<<<dim3(98, 8), 256, 0, stream>>>(yfT, kv_w, kv_b, kh_, vh_, 1.0f);
    hipFuncSetAttribute(reinterpret_cast<const void*>(attn_kernel),
                        hipFuncAttributeMaxDynamicSharedMemorySize, ATTN_SMEM);
    attn_kernel<<<dim3(N_ / ROWS, B_ * NH_), 1024, ATTN_SMEM, stream>>>(qh_, kh_, vh_, a1p, a2p, aoT);
    gemm_proj<<<dim3(98, 4), 256, 0, stream>>>(aoT, p_w, p_b, out);
}

// Round 4
// 943.346 us; speedup vs baseline: 1.7865x; 1.0735x over previous
//
#include <hip/hip_runtime.h>

#define B_    2
#define C_    256
#define HW_   56
#define N_    3136     // 56*56
#define NH_   8
#define D_    32
#define K1CNT 1568     // N_/2
#define K2CNT 1045     // N_//3
#define LN_EPS 1e-5f
#define SROW  3140     // padded score row; 3140%32==4
#define ROWS  4        // q-rows per block
#define PROBS 8        // ROWS * 2 top-k problems
#define NBIN  1024     // w-space bins: 8 exponents x 128 mantissa slots
#define WBASE 14336    // (127-15)<<7 ; covers w=exp(s-8) for s in (-2.40, 3.15)
#define HISTW 2048     // ROWS * 512 u32 words (u16-packed bin pairs)
#define CAP   256      // candidate capacity per problem (~25 expected per bin)
#define RM    8.0f     // row-uniform exp shift (softmax shift-invariant; |s| << 8)

// LDS: S 50240 | X 8192 (hist -> cand -> red, disjoint lifetimes) | misc
// total ~58.7 KB  ->  2 blocks/CU (32 waves = CU wave cap)

// full-wave sum: xor-butterfly via ds_swizzle + cross-32 shfl
__device__ inline float redsum64(float v) {
    v += __int_as_float(__builtin_amdgcn_ds_swizzle(__float_as_int(v), 0x041F)); // xor 1
    v += __int_as_float(__builtin_amdgcn_ds_swizzle(__float_as_int(v), 0x081F)); // xor 2
    v += __int_as_float(__builtin_amdgcn_ds_swizzle(__float_as_int(v), 0x101F)); // xor 4
    v += __int_as_float(__builtin_amdgcn_ds_swizzle(__float_as_int(v), 0x201F)); // xor 8
    v += __int_as_float(__builtin_amdgcn_ds_swizzle(__float_as_int(v), 0x401F)); // xor 16
    v += __shfl_xor(v, 32, 64);
    return v;
}

// sum over jj4 groups (xor 8,16,32)
__device__ inline float avred(float v) {
    v += __int_as_float(__builtin_amdgcn_ds_swizzle(__float_as_int(v), 0x201F)); // xor 8
    v += __int_as_float(__builtin_amdgcn_ds_swizzle(__float_as_int(v), 0x401F)); // xor 16
    v += __shfl_xor(v, 32, 64);
    return v;
}

// ---------------- pooling (3 avg pools summed, zero-pad, divisor k*k) -------
__global__ void pool_kernel(const float* __restrict__ y, float* __restrict__ yp)
{
    int gid = blockIdx.x * 256 + threadIdx.x;
    int n  = gid % N_;
    int bc = gid / N_;
    const float* src = y + (size_t)bc * N_;
    int x0 = n % HW_, y0 = n / HW_;
    float acc = 0.f;
#pragma unroll
    for (int dy = -3; dy <= 3; ++dy) {
        int yy = y0 + dy;
        if ((unsigned)yy >= HW_) continue;
#pragma unroll
        for (int dx = -3; dx <= 3; ++dx) {
            int xx = x0 + dx;
            if ((unsigned)xx >= HW_) continue;
            float w = 1.f / 49.f;
            if (dy >= -2 && dy <= 2 && dx >= -2 && dx <= 2) w += 1.f / 25.f;
            if (dy >= -1 && dy <= 1 && dx >= -1 && dx <= 1) w += 1.f / 9.f;
            acc += w * src[yy * HW_ + xx];
        }
    }
    yp[gid] = acc;
}

// ---------------- layernorm over C, writes transposed [B,C,N] ---------------
__global__ void ln_kernel(const float* __restrict__ yp, const float* __restrict__ lnw,
                          const float* __restrict__ lnb, float* __restrict__ yfT)
{
    __shared__ float wr[8];
    __shared__ float stats[2];
    int idx = blockIdx.x;
    int b = idx / N_, n = idx % N_;
    int c = threadIdx.x;
    size_t off = ((size_t)b * C_ + c) * N_ + n;
    float v = yp[off];
    float s = v, q = v * v;
    int lane = threadIdx.x & 63, wid = threadIdx.x >> 6;
#pragma unroll
    for (int d = 32; d; d >>= 1) { s += __shfl_down(s, d, 64); q += __shfl_down(q, d, 64); }
    if (lane == 0) { wr[wid] = s; wr[4 + wid] = q; }
    __syncthreads();
    if (threadIdx.x == 0) {
        float ts = wr[0] + wr[1] + wr[2] + wr[3];
        float tq = wr[4] + wr[5] + wr[6] + wr[7];
        float mu = ts * (1.f / C_);
        float var = tq * (1.f / C_) - mu * mu;
        stats[0] = mu; stats[1] = rsqrtf(var + LN_EPS);
    }
    __syncthreads();
    yfT[off] = (v - stats[0]) * stats[1] * lnw[c] + lnb[c];
}

// ---------------- GEMM: out = A(AT layout [B,C,N]) @ W[O,K]^T + bias --------
__global__ __launch_bounds__(256) void gemm_qkv(
    const float* __restrict__ A, const float* __restrict__ W,
    const float* __restrict__ bias, float* __restrict__ dst0,
    float* __restrict__ dst1, float scale)
{
    __shared__ float As[16][64];
    __shared__ float Ws[16][68];
    int tid = threadIdx.x;
    int m0 = blockIdx.x * 64;
    int b = m0 / N_, n0 = m0 % N_;
    int o0 = blockIdx.y * 64;
    const float* Ab = A + (size_t)b * C_ * N_;
    float acc[4][4] = {};
    int la_k = tid >> 4;
    int la_m = (tid & 15) * 4;
    int lw_o = tid >> 2;
    int lw_k = (tid & 3) * 4;
    int u  = tid & 15;
    int v_ = tid >> 4;
    for (int kt = 0; kt < 16; ++kt) {
        int k0 = kt * 16;
        float4 av = *(const float4*)&Ab[(size_t)(k0 + la_k) * N_ + n0 + la_m];
        float4 wv = *(const float4*)&W[(size_t)(o0 + lw_o) * C_ + k0 + lw_k];
        __syncthreads();
        *(float4*)&As[la_k][la_m] = av;
        Ws[lw_k + 0][lw_o] = wv.x; Ws[lw_k + 1][lw_o] = wv.y;
        Ws[lw_k + 2][lw_o] = wv.z; Ws[lw_k + 3][lw_o] = wv.w;
        __syncthreads();
#pragma unroll
        for (int k = 0; k < 16; ++k) {
            float4 wf = *(const float4*)&Ws[k][u * 4];
            float a0 = As[k][v_], a1 = As[k][v_ + 16], a2 = As[k][v_ + 32], a3 = As[k][v_ + 48];
            acc[0][0] += wf.x * a0; acc[0][1] += wf.x * a1; acc[0][2] += wf.x * a2; acc[0][3] += wf.x * a3;
            acc[1][0] += wf.y * a0; acc[1][1] += wf.y * a1; acc[1][2] += wf.y * a2; acc[1][3] += wf.y * a3;
            acc[2][0] += wf.z * a0; acc[2][1] += wf.z * a1; acc[2][2] += wf.z * a2; acc[2][3] += wf.z * a3;
            acc[3][0] += wf.w * a0; acc[3][1] += wf.w * a1; acc[3][2] += wf.w * a2; acc[3][3] += wf.w * a3;
        }
    }
    int oc = o0 + u * 4;
    float b0v = bias[oc], b1v = bias[oc + 1], b2v = bias[oc + 2], b3v = bias[oc + 3];
    float* dst = dst0; int c2 = oc;
    if (dst1 && oc >= C_) { dst = dst1; c2 = oc - C_; }
    int h = c2 >> 5, d0 = c2 & 31;
    size_t base = ((size_t)b * NH_ + h) * N_ * D_;
#pragma unroll
    for (int j = 0; j < 4; ++j) {
        int n = n0 + v_ + j * 16;
        float4 val;
        val.x = (acc[0][j] + b0v) * scale;
        val.y = (acc[1][j] + b1v) * scale;
        val.z = (acc[2][j] + b2v) * scale;
        val.w = (acc[3][j] + b3v) * scale;
        *(float4*)&dst[base + (size_t)n * D_ + d0] = val;
    }
}

__global__ __launch_bounds__(256) void gemm_proj(
    const float* __restrict__ A, const float* __restrict__ W,
    const float* __restrict__ bias, float* __restrict__ out)
{
    __shared__ float As[16][64];
    __shared__ float Ws[16][68];
    int tid = threadIdx.x;
    int m0 = blockIdx.x * 64;
    int b = m0 / N_, n0 = m0 % N_;
    int o0 = blockIdx.y * 64;
    const float* Ab = A + (size_t)b * C_ * N_;
    float acc[4][4] = {};
    int la_k = tid >> 4;
    int la_m = (tid & 15) * 4;
    int lw_o = tid >> 2;
    int lw_k = (tid & 3) * 4;
    int u  = tid & 15;
    int v_ = tid >> 4;
    for (int kt = 0; kt < 16; ++kt) {
        int k0 = kt * 16;
        float4 av = *(const float4*)&Ab[(size_t)(k0 + la_k) * N_ + n0 + la_m];
        float4 wv = *(const float4*)&W[(size_t)(o0 + lw_o) * C_ + k0 + lw_k];
        __syncthreads();
        *(float4*)&As[la_k][la_m] = av;
        Ws[lw_k + 0][lw_o] = wv.x; Ws[lw_k + 1][lw_o] = wv.y;
        Ws[lw_k + 2][lw_o] = wv.z; Ws[lw_k + 3][lw_o] = wv.w;
        __syncthreads();
#pragma unroll
        for (int k = 0; k < 16; ++k) {
            float4 af = *(const float4*)&As[k][u * 4];
            float w0 = Ws[k][v_], w1 = Ws[k][v_ + 16], w2 = Ws[k][v_ + 32], w3 = Ws[k][v_ + 48];
            acc[0][0] += w0 * af.x; acc[0][1] += w0 * af.y; acc[0][2] += w0 * af.z; acc[0][3] += w0 * af.w;
            acc[1][0] += w1 * af.x; acc[1][1] += w1 * af.y; acc[1][2] += w1 * af.z; acc[1][3] += w1 * af.w;
            acc[2][0] += w2 * af.x; acc[2][1] += w2 * af.y; acc[2][2] += w2 * af.z; acc[2][3] += w2 * af.w;
            acc[3][0] += w3 * af.x; acc[3][1] += w3 * af.y; acc[3][2] += w3 * af.z; acc[3][3] += w3 * af.w;
        }
    }
#pragma unroll
    for (int i = 0; i < 4; ++i) {
        int o = o0 + v_ + i * 16;
        float bb = bias[o];
        float4 val;
        val.x = acc[i][0] + bb; val.y = acc[i][1] + bb;
        val.z = acc[i][2] + bb; val.w = acc[i][3] + bb;
        *(float4*)&out[((size_t)b * C_ + o) * N_ + n0 + u * 4] = val;
    }
}

// ---------------- fused attention (1024 threads, 16 waves, 4 q-rows) --------
// w-space selection: S holds w = exp(s - RM) > 0; float order == unsigned bit
// order, so all thresholds are plain u32 compares and no exp/ordf downstream.
struct AttnMisc {
    unsigned thrBin[PROBS];
    int selrM[PROBS];
    unsigned thrU[PROBS];
    unsigned cntM[PROBS];
    float coef[PROBS];
    float pp[2];
    float wred[32];      // 16 waves x {dsum1, dsum2} of its row
};

// radix refine over low 16 bits + boundary sum of candidate w's (in regs)
#define REFINE_BSUM(NV)                                                    \
    {                                                                      \
        unsigned vv[NV]; unsigned aok = 0;                                 \
        _Pragma("unroll")                                                  \
        for (int t = 0; t < NV; ++t) {                                     \
            int idx = lane + (t << 6);                                     \
            bool ok = idx < cnt;                                           \
            vv[t] = ok ? cp[idx] : 0u;                                     \
            if (ok) aok |= 1u << t;                                        \
        }                                                                  \
        unsigned act = aok;                                                \
        for (int b = 15; b >= 0; --b) {                                    \
            unsigned msk = 0, c = 0;                                       \
            _Pragma("unroll")                                              \
            for (int t = 0; t < NV; ++t) {                                 \
                bool p = ((act >> t) & 1u) && ((vv[t] >> b) & 1u);         \
                c += (unsigned)__popcll(__ballot(p));                      \
                if (p) msk |= 1u << t;                                     \
            }                                                              \
            if (c >= kk) { act = msk; bits |= 1u << b; }                   \
            else { kk -= c; act &= ~msk; }                                 \
        }                                                                  \
        unsigned thr = lo | bits;                                          \
        _Pragma("unroll")                                                  \
        for (int t = 0; t < NV; ++t) {                                     \
            if (((aok >> t) & 1u) && vv[t] >= thr)                         \
                bsum += __uint_as_float(vv[t]);                            \
        }                                                                  \
    }

__global__ __launch_bounds__(1024, 8) void attn_kernel(
    const float* __restrict__ qh, const float* __restrict__ kh, const float* __restrict__ vh,
    const float* __restrict__ p1p, const float* __restrict__ p2p,
    float* __restrict__ aoT)
{
    extern __shared__ char smem[];
    float*    S    = (float*)smem;                    // 4*3140 f32 = 50240 B
    unsigned* hist = (unsigned*)(smem + 50240);       // 4*512 u32 (u16-packed)
    unsigned* cand = (unsigned*)(smem + 50240);       // 8*256 u32 (after search)
    float*    red  = (float*)(smem + 50240);          // 16*128 f32 (AV epilogue)
    AttnMisc* M    = (AttnMisc*)(smem + 50240 + 8192);

    int tid = threadIdx.x, lane = tid & 63, wid = tid >> 6;
    int bh = blockIdx.y, n0 = blockIdx.x * ROWS;
    size_t bhN = (size_t)bh * N_;

    if (tid < PROBS) M->cntM[tid] = 0u;
    if (tid == 0) { M->pp[0] = p1p[0]; M->pp[1] = p2p[0]; }
    if (tid < HISTW) hist[tid] = 0u;
    if (tid + 1024 < HISTW) hist[tid + 1024] = 0u;
    __syncthreads();

    // ---- P0: w = exp(s-RM) + fine w-space histogram ----
    const float* qrow = qh + (bhN + n0) * D_;
    for (int i = 0; i < 4; ++i) {
        int j = tid + (i << 10);
        if (j < N_) {
            const float4* kp = (const float4*)(kh + (bhN + j) * D_);
            float4 k4[8];
#pragma unroll
            for (int q = 0; q < 8; ++q) k4[q] = kp[q];
#pragma unroll
            for (int r = 0; r < ROWS; ++r) {
                const float4* qp = (const float4*)(qrow + r * D_);
                float s = 0.f;
#pragma unroll
                for (int q = 0; q < 8; ++q) {
                    float4 q4 = qp[q];
                    s += q4.x * k4[q].x + q4.y * k4[q].y + q4.z * k4[q].z + q4.w * k4[q].w;
                }
                float w = __expf(s - RM);
                S[r * SROW + j] = w;
                int bin = (int)(__float_as_uint(w) >> 16) - WBASE;
                bin = max(0, min(bin, NBIN - 1));
                atomicAdd(&hist[(r << 9) + (bin >> 1)], 1u << ((bin & 1) << 4));
            }
        }
    }
    __syncthreads();

    // ---- histogram search (wave w -> problem w, w<8): 16 bins per lane ----
    if (wid < PROBS) {
        int prob = wid;
        int r = prob >> 1;
        int k = (prob & 1) ? K2CNT : K1CNT;
        const unsigned* hrow = hist + (r << 9) + (lane << 3);
        uint4 ha = *(const uint4*)(hrow + 0);
        uint4 hb = *(const uint4*)(hrow + 4);
        unsigned hh[8] = { ha.x, ha.y, ha.z, ha.w, hb.x, hb.y, hb.z, hb.w };
        unsigned usum = 0;
#pragma unroll
        for (int t = 0; t < 8; ++t) usum += hh[t];
        int ltot = (int)((usum & 0xFFFFu) + (usum >> 16));   // row total <= 3136: no carry
        int s = ltot;
#pragma unroll
        for (int d = 1; d < 64; d <<= 1) {
            int o = __shfl_down(s, d, 64);
            if (lane + d < 64) s += o;
        }
        int after = s - ltot;            // counts in higher lanes' (larger) bins
        if (after < k && after + ltot >= k) {   // crossing lane (unique)
            int g = after, b0 = -1, selr = 0;
#pragma unroll
            for (int m = 15; m >= 0; --m) {
                unsigned w = hh[m >> 1];
                int cm = (m & 1) ? (int)(w >> 16) : (int)(w & 0xFFFFu);
                g += cm;
                if (b0 < 0 && g >= k) { b0 = (lane << 4) + m; selr = k - (g - cm); }
            }
            M->thrBin[prob] = (unsigned)b0;
            M->selrM[prob] = selr;
        }
    }
    __syncthreads();

    // ---- P1: gather candidates + definite exp-sums (row-per-wave-group) ----
    {
        int row = wid >> 2;
        int sub = ((wid & 3) << 6) | lane;      // 0..255 within row group
        unsigned lo1 = (unsigned)(WBASE + M->thrBin[2 * row]) << 16, hi1 = lo1 + 0x10000u;
        unsigned lo2 = (unsigned)(WBASE + M->thrBin[2 * row + 1]) << 16, hi2 = lo2 + 0x10000u;
        int p1 = 2 * row, p2 = 2 * row + 1;
        float ds1 = 0.f, ds2 = 0.f;
        const float* Srow = S + row * SROW;
#pragma unroll
        for (int i = 0; i < 4; ++i) {
            int q = sub + (i << 8);
            if (q < 784) {                       // 784 quads * 4 = 3136
                float4 sv = *(const float4*)&Srow[q << 2];
                float sa[4] = { sv.x, sv.y, sv.z, sv.w };
#pragma unroll
                for (int t = 0; t < 4; ++t) {
                    unsigned u = __float_as_uint(sa[t]);
                    if (u >= hi1) {
                        ds1 += sa[t];
                        if (u >= hi2) ds2 += sa[t];
                    } else if (u >= lo1) {
                        unsigned ix = atomicAdd(&M->cntM[p1], 1u);
                        if (ix < CAP) cand[p1 * CAP + ix] = u;
                    }
                    if (u >= lo2 && u < hi2) {
                        unsigned ix = atomicAdd(&M->cntM[p2], 1u);
                        if (ix < CAP) cand[p2 * CAP + ix] = u;
                    }
                }
            }
        }
        ds1 = redsum64(ds1);
        ds2 = redsum64(ds2);
        if (lane == 0) { M->wred[wid * 2] = ds1; M->wred[wid * 2 + 1] = ds2; }
    }
    __syncthreads();

    // ---- refine (16-bit ballot-radix) + boundary sums + coef ----
    if (wid < PROBS) {
        int prob = wid;
        int cnt = (int)M->cntM[prob]; if (cnt > CAP) cnt = CAP;
        unsigned kk = (unsigned)M->selrM[prob];
        unsigned lo = (unsigned)(WBASE + M->thrBin[prob]) << 16;
        const unsigned* cp = cand + prob * CAP;
        unsigned bits = 0;
        float bsum = 0.f;
        if (cnt <= 64)       REFINE_BSUM(1)
        else if (cnt <= 128) REFINE_BSUM(2)
        else                 REFINE_BSUM(4)
        bsum = redsum64(bsum);
        if (lane == 0) {
            M->thrU[prob] = lo | bits;
            int rw = (prob >> 1) << 2;           // first wave of this row's group
            float denom = bsum
                + M->wred[(rw + 0) * 2 + (prob & 1)]
                + M->wred[(rw + 1) * 2 + (prob & 1)]
                + M->wred[(rw + 2) * 2 + (prob & 1)]
                + M->wred[(rw + 3) * 2 + (prob & 1)];
            M->coef[prob] = M->pp[prob & 1] / denom;
        }
    }
    __syncthreads();

    // ---- transform: w -> final AV coefficient (no exp, no ordf) ----
    {
        int row = wid >> 2;
        int sub = ((wid & 3) << 6) | lane;
        unsigned u1 = M->thrU[2 * row], u2 = M->thrU[2 * row + 1];
        float c1 = M->coef[2 * row];
        float c12 = c1 + M->coef[2 * row + 1];
        float* Srow = S + row * SROW;
#pragma unroll
        for (int i = 0; i < 4; ++i) {
            int q = sub + (i << 8);
            if (q < 784) {
                float4 sv = *(const float4*)&Srow[q << 2];
                float sa[4] = { sv.x, sv.y, sv.z, sv.w };
#pragma unroll
                for (int t = 0; t < 4; ++t) {
                    unsigned u = __float_as_uint(sa[t]);
                    float sel = (u >= u2) ? c12 : c1;
                    sa[t] = (u >= u1) ? sa[t] * sel : 0.f;
                }
                *(float4*)&Srow[q << 2] = make_float4(sa[0], sa[1], sa[2], sa[3]);
            }
        }
    }
    __syncthreads();

    // ---- AV: 32-j groups, V direct from global (L2-resident), reg accumulate ----
    int jj4 = lane >> 3, dq = lane & 7;
    float4 acc[ROWS];
#pragma unroll
    for (int r = 0; r < ROWS; ++r) acc[r] = make_float4(0.f, 0.f, 0.f, 0.f);
    const float* vbase = vh + bhN * D_ + (dq << 2);
    for (int g = wid; g < 98; g += 16) {        // 98 groups of 32 j
        int jb = (g << 5) + (jj4 << 2);
        float4 v0 = *(const float4*)(vbase + (size_t)(jb + 0) * D_);
        float4 v1 = *(const float4*)(vbase + (size_t)(jb + 1) * D_);
        float4 v2 = *(const float4*)(vbase + (size_t)(jb + 2) * D_);
        float4 v3 = *(const float4*)(vbase + (size_t)(jb + 3) * D_);
#pragma unroll
        for (int r = 0; r < ROWS; ++r) {
            float4 s4 = *(const float4*)&S[r * SROW + jb];
            acc[r].x += s4.x * v0.x + s4.y * v1.x + s4.z * v2.x + s4.w * v3.x;
            acc[r].y += s4.x * v0.y + s4.y * v1.y + s4.z * v2.y + s4.w * v3.y;
            acc[r].z += s4.x * v0.z + s4.y * v1.z + s4.z * v2.z + s4.w * v3.z;
            acc[r].w += s4.x * v0.w + s4.y * v1.w + s4.z * v2.w + s4.w * v3.w;
        }
    }
#pragma unroll
    for (int r = 0; r < ROWS; ++r) {
        acc[r].x = avred(acc[r].x);
        acc[r].y = avred(acc[r].y);
        acc[r].z = avred(acc[r].z);
        acc[r].w = avred(acc[r].w);
    }
    if (lane < 8) {
#pragma unroll
        for (int r = 0; r < ROWS; ++r)
            *(float4*)&red[(wid << 7) + (r << 5) + (lane << 2)] = acc[r];
    }
    __syncthreads();
    if (tid < 32 * ROWS) {
        float o = 0.f;
#pragma unroll
        for (int w = 0; w < 16; ++w) o += red[(w << 7) + tid];
        int r = tid >> 5, d = tid & 31;
        int b = bh >> 3, h = bh & 7;
        aoT[((size_t)(b * C_ + h * 32 + d)) * N_ + n0 + r] = o;
    }
}

static const int ATTN_SMEM = 50240 + 8192 + (int)sizeof(AttnMisc);

extern "C" void kernel_launch(void* const* d_in, const int* in_sizes, int n_in,
                              void* d_out, int out_size, void* d_ws, size_t ws_size,
                              hipStream_t stream)
{
    (void)in_sizes; (void)n_in; (void)out_size; (void)ws_size;
    const float* x    = (const float*)d_in[0];
    const float* y    = (const float*)d_in[1];
    const float* q_w  = (const float*)d_in[2];
    const float* q_b  = (const float*)d_in[3];
    const float* kv_w = (const float*)d_in[4];
    const float* kv_b = (const float*)d_in[5];
    const float* p_w  = (const float*)d_in[6];
    const float* p_b  = (const float*)d_in[7];
    const float* lnw  = (const float*)d_in[8];
    const float* lnb  = (const float*)d_in[9];
    const float* a1p  = (const float*)d_in[10];
    const float* a2p  = (const float*)d_in[11];
    float* out = (float*)d_out;

    float* ws = (float*)d_ws;
    const size_t PLANE = (size_t)B_ * C_ * N_;
    float* yp  = ws;
    float* yfT = ws + PLANE;
    float* qh_ = ws + 2 * PLANE;
    float* kh_ = ws + 3 * PLANE;
    float* vh_ = ws + 4 * PLANE;
    float* aoT = ws + 5 * PLANE;

    pool_kernel<<<dim3((unsigned)(PLANE / 256)), 256, 0, stream>>>(y, yp);
    ln_kernel<<<dim3(B_ * N_), 256, 0, stream>>>(yp, lnw, lnb, yfT);
    gemm_qkv<<<dim3(98, 4), 256, 0, stream>>>(x, q_w, q_b, qh_, nullptr, 0.17677669529663687f);
    gemm_qkv<<<dim3(98, 8), 256, 0, stream>>>(yfT, kv_w, kv_b, kh_, vh_, 1.0f);
    hipFuncSetAttribute(reinterpret_cast<const void*>(attn_kernel),
                        hipFuncAttributeMaxDynamicSharedMemorySize, ATTN_SMEM);
    attn_kernel<<<dim3(N_ / ROWS, B_ * NH_), 1024, ATTN_SMEM, stream>>>(qh_, kh_, vh_, a1p, a2p, aoT);
    gemm_proj<<<dim3(98, 4), 256, 0, stream>>>(aoT, p_w, p_b, out);
}